// Round 1
// 200.982 us; speedup vs baseline: 1.0106x; 1.0106x over previous
//
#include <hip/hip_runtime.h>
#include <math.h>

// CapsuleLayer dynamic routing. C=32,B=32,N=4096,IN=16,OUT=32, 3 iters.
// v9: v8 structure + fused W->f16 materialization.
//   - sweep0 reads W f32 (nontemporal: zero reuse now) and, besides the
//     MFMA, stores the already-converted f16 A-fragments to workspace Wt in
//     exact fragment layout (1 coalesced 16B store/lane/tile). 128 MB, lands
//     in the freshly-flushed L3 and stays resident (nt reads don't evict it).
//   - sweeps 1-2 read Wt: half the bytes, from L3 instead of HBM, and one
//     dwordx4 A-load per tile instead of 8 strided dwords + 8 cvts.
//   - numerics identical to v8 (same f16 values, same accumulation order).
// Per (c,n): D[d][b] = W[c,n](32d x 16i) . xt[n](16i x 32b) via
// v_mfma_f32_32x32x16_f16 (C/D: col(lane&31)=b, row(reg)=d). d on M axis
// makes the routing logit dot register-local.

typedef _Float16 f16x8 __attribute__((ext_vector_type(8)));
typedef float f32x16 __attribute__((ext_vector_type(16)));

namespace {
constexpr int kC = 32, kB = 32, kN = 4096, kI = 16, kD = 32;
constexpr int CHUNKS = 32;            // n-chunks per c
constexpr int CHUNK_N = kN / CHUNKS;  // 128
constexpr int PS = kB * kD + kB;      // 1056 floats per (c,chunk) partial
constexpr int GRID = kC * CHUNKS;     // 1024 blocks
constexpr size_t XT_ELEMS = (size_t)kN * kB * kI;       // f16 [n][b][i]
constexpr size_t WT_ELEMS = (size_t)kC * kN * kI * kD;  // f16 fragment layout
constexpr size_t P_FLOATS = (size_t)kC * CHUNKS * PS;
constexpr size_t CV_FLOATS = (size_t)kC * kB * kD;
constexpr size_t WS_BYTES_MID = XT_ELEMS * 2 + (P_FLOATS + CV_FLOATS) * 4;
constexpr size_t WS_BYTES_BIG =
    (XT_ELEMS + WT_ELEMS) * 2 + (P_FLOATS + CV_FLOATS) * 4;
}  // namespace

__device__ __forceinline__ f32x16 zero16() {
  f32x16 z;
#pragma unroll
  for (int r = 0; r < 16; ++r) z[r] = 0.f;
  return z;
}

// ---- k_xt: x[b][n][i] f32 -> xt[n][b][i] f16 (1024 blocks, half-row/thr) --
__global__ __launch_bounds__(256) void k_xt(const float* __restrict__ x,
                                            _Float16* __restrict__ xt) {
  const int t = blockIdx.x * 256 + threadIdx.x;  // [0, 262144) == 2*B*N
  const int r = t >> 1, half = t & 1;            // r = b*4096 + n
  const int b = r >> 12, n = r & 4095;
  const float4* s4 =
      reinterpret_cast<const float4*>(x) + (size_t)r * 4 + half * 2;
  const float4 f0 = s4[0], f1 = s4[1];
  f16x8 o;
  o[0] = (_Float16)f0.x; o[1] = (_Float16)f0.y;
  o[2] = (_Float16)f0.z; o[3] = (_Float16)f0.w;
  o[4] = (_Float16)f1.x; o[5] = (_Float16)f1.y;
  o[6] = (_Float16)f1.z; o[7] = (_Float16)f1.w;
  *reinterpret_cast<f16x8*>(xt + ((size_t)n * kB + b) * kI + half * 8) = o;
}

// ---- k_sweep<MODE,EMIT>: MFMA sweep reading W f32 directly ----
// MODE 0: uniform probs (acc in MFMA C operand). MODE 1: softmax(prior.cv).
// EMIT: additionally store the converted f16 A-fragments to Wt (MODE 0 only),
// with nontemporal W reads (W has zero reuse in that configuration).
template <int MODE, bool EMIT>
__global__ __launch_bounds__(256) void k_sweep(const float* __restrict__ W,
                                               const _Float16* __restrict__ xt,
                                               const float* __restrict__ cumVec,
                                               float* __restrict__ partials,
                                               _Float16* __restrict__ Wt) {
  __shared__ float red[4][32][33];
  __shared__ float lred[4][32];
  const int bid = blockIdx.x;
  const int c = bid & 31;  // same-c blocks on one XCD
  const int chunk = bid >> 5;
  const int tid = threadIdx.x;
  const int w = tid >> 6, l = tid & 63;
  const int m = l & 31, h = l >> 5;
  const int n0 = chunk * CHUNK_N;
  constexpr int TILES = CHUNK_N / 4;  // 32 per wave, waves interleave by 4

  // A-source: W[c, n][i][d] f32, lane (m=d, h) reads i = h*8+j at d=m.
  const float* wp = W + ((size_t)c * kN + n0 + w) * 512 + (h * 8) * 32 + m;
  // B-source: xt[n][b][i] f16, lane (m=b, h) reads 8 consecutive i.
  const _Float16* xp = xt + ((size_t)(n0 + w)) * 512 + m * 16 + h * 8;
  // Wt fragment store base: per n 512 f16, lane l owns [l*8, l*8+8).
  _Float16* wtp =
      EMIT ? (Wt + ((size_t)c * kN + n0 + w) * 512 + (size_t)l * 8) : nullptr;

  float cvr[16];
  if (MODE) {
    const float* cvp = cumVec + (size_t)c * 1024 + m * 32;
#pragma unroll
    for (int r = 0; r < 16; ++r) cvr[r] = cvp[(r & 3) + 8 * (r >> 2) + 4 * h];
  }

  f32x16 accA = zero16(), accB = zero16();
  float lacc = 0.f;
  const f32x16 z = zero16();

  // 2-deep prefetch ring, static slots (manual 2-step unroll).
  float rA0[8], rA1[8];
  f16x8 B0, B1;
#pragma unroll
  for (int j = 0; j < 8; ++j)
    rA0[j] = EMIT ? __builtin_nontemporal_load(wp + j * 32) : wp[j * 32];
  B0 = *reinterpret_cast<const f16x8*>(xp);
#pragma unroll
  for (int j = 0; j < 8; ++j)
    rA1[j] = EMIT ? __builtin_nontemporal_load(wp + 2048 + j * 32)
                  : wp[2048 + j * 32];
  B1 = *reinterpret_cast<const f16x8*>(xp + 2048);

#pragma unroll 1
  for (int t = 0; t < TILES; t += 2) {
    // ---- tile t (slot 0) ----
    {
      f16x8 a;
#pragma unroll
      for (int j = 0; j < 8; ++j) a[j] = (_Float16)rA0[j];
      const f16x8 b = B0;
      const int tn = (t + 2 < TILES) ? t + 2 : 0;  // clamp: no OOB on W
#pragma unroll
      for (int j = 0; j < 8; ++j)
        rA0[j] = EMIT ? __builtin_nontemporal_load(wp + (size_t)tn * 2048 +
                                                   j * 32)
                      : wp[(size_t)tn * 2048 + j * 32];
      B0 = *reinterpret_cast<const f16x8*>(xp + (size_t)tn * 2048);
      if constexpr (EMIT)
        *reinterpret_cast<f16x8*>(wtp + (size_t)t * 2048) = a;
      if constexpr (MODE == 0) {
        accA = __builtin_amdgcn_mfma_f32_32x32x16_f16(a, b, accA, 0, 0, 0);
      } else {
        const f32x16 pr =
            __builtin_amdgcn_mfma_f32_32x32x16_f16(a, b, z, 0, 0, 0);
        float d0 = pr[0] * cvr[0], d1 = pr[1] * cvr[1];
        float d2 = pr[2] * cvr[2], d3 = pr[3] * cvr[3];
#pragma unroll
        for (int r = 4; r < 16; r += 4) {
          d0 = fmaf(pr[r + 0], cvr[r + 0], d0);
          d1 = fmaf(pr[r + 1], cvr[r + 1], d1);
          d2 = fmaf(pr[r + 2], cvr[r + 2], d2);
          d3 = fmaf(pr[r + 3], cvr[r + 3], d3);
        }
        float dp = (d0 + d1) + (d2 + d3);
        dp += __shfl_xor(dp, 32);  // combine the two k-halves
        const float e = __expf(dp);
        lacc += e;
#pragma unroll
        for (int r = 0; r < 16; ++r) accA[r] = fmaf(e, pr[r], accA[r]);
      }
    }
    // ---- tile t+1 (slot 1) ----
    {
      f16x8 a;
#pragma unroll
      for (int j = 0; j < 8; ++j) a[j] = (_Float16)rA1[j];
      const f16x8 b = B1;
      const int tn = (t + 3 < TILES) ? t + 3 : 0;
#pragma unroll
      for (int j = 0; j < 8; ++j)
        rA1[j] = EMIT ? __builtin_nontemporal_load(wp + (size_t)tn * 2048 +
                                                   j * 32)
                      : wp[(size_t)tn * 2048 + j * 32];
      B1 = *reinterpret_cast<const f16x8*>(xp + (size_t)tn * 2048);
      if constexpr (EMIT)
        *reinterpret_cast<f16x8*>(wtp + (size_t)(t + 1) * 2048) = a;
      if constexpr (MODE == 0) {
        accB = __builtin_amdgcn_mfma_f32_32x32x16_f16(a, b, accB, 0, 0, 0);
      } else {
        const f32x16 pr =
            __builtin_amdgcn_mfma_f32_32x32x16_f16(a, b, z, 0, 0, 0);
        float d0 = pr[0] * cvr[0], d1 = pr[1] * cvr[1];
        float d2 = pr[2] * cvr[2], d3 = pr[3] * cvr[3];
#pragma unroll
        for (int r = 4; r < 16; r += 4) {
          d0 = fmaf(pr[r + 0], cvr[r + 0], d0);
          d1 = fmaf(pr[r + 1], cvr[r + 1], d1);
          d2 = fmaf(pr[r + 2], cvr[r + 2], d2);
          d3 = fmaf(pr[r + 3], cvr[r + 3], d3);
        }
        float dp = (d0 + d1) + (d2 + d3);
        dp += __shfl_xor(dp, 32);
        const float e = __expf(dp);
        lacc += e;
#pragma unroll
        for (int r = 0; r < 16; ++r) accB[r] = fmaf(e, pr[r], accB[r]);
      }
    }
  }
#pragma unroll
  for (int r = 0; r < 16; ++r) accA[r] += accB[r];

  // block reduce across 4 waves; partial layout P[d*32+b] (+ denom at 1024+b)
#pragma unroll
  for (int r = 0; r < 16; ++r)
    red[w][(r & 3) + 8 * (r >> 2) + 4 * h][m] = accA[r];
  if (MODE && h == 0) lred[w][m] = lacc;  // e identical in both halves
  __syncthreads();

  float* Pp = partials + ((size_t)c * CHUNKS + chunk) * PS;
#pragma unroll
  for (int e = tid; e < 1024; e += 256) {
    const int d = e >> 5, bb = e & 31;
    Pp[e] = red[0][d][bb] + red[1][d][bb] + red[2][d][bb] + red[3][d][bb];
  }
  if (MODE && tid < 32)
    Pp[1024 + tid] = lred[0][tid] + lred[1][tid] + lred[2][tid] + lred[3][tid];
}

// ---- k_sweep_wt: MODE-1 sweep reading pre-converted Wt f16 fragments ----
// Per tile: one dwordx4 A load (fragment layout) + one dwordx4 B load.
__global__ __launch_bounds__(256) void k_sweep_wt(
    const _Float16* __restrict__ Wt, const _Float16* __restrict__ xt,
    const float* __restrict__ cumVec, float* __restrict__ partials) {
  __shared__ float red[4][32][33];
  __shared__ float lred[4][32];
  const int bid = blockIdx.x;
  const int c = bid & 31;
  const int chunk = bid >> 5;
  const int tid = threadIdx.x;
  const int w = tid >> 6, l = tid & 63;
  const int m = l & 31, h = l >> 5;
  const int n0 = chunk * CHUNK_N;
  constexpr int TILES = CHUNK_N / 4;

  const _Float16* wp = Wt + ((size_t)c * kN + n0 + w) * 512 + (size_t)l * 8;
  const _Float16* xp = xt + ((size_t)(n0 + w)) * 512 + m * 16 + h * 8;

  float cvr[16];
  const float* cvp = cumVec + (size_t)c * 1024 + m * 32;
#pragma unroll
  for (int r = 0; r < 16; ++r) cvr[r] = cvp[(r & 3) + 8 * (r >> 2) + 4 * h];

  f32x16 accA = zero16(), accB = zero16();
  float lacc = 0.f;
  const f32x16 z = zero16();

  f16x8 A0, A1, B0, B1;
  A0 = *reinterpret_cast<const f16x8*>(wp);
  B0 = *reinterpret_cast<const f16x8*>(xp);
  A1 = *reinterpret_cast<const f16x8*>(wp + 2048);
  B1 = *reinterpret_cast<const f16x8*>(xp + 2048);

#pragma unroll 1
  for (int t = 0; t < TILES; t += 2) {
    // ---- tile t (slot 0) ----
    {
      const f16x8 a = A0;
      const f16x8 b = B0;
      const int tn = (t + 2 < TILES) ? t + 2 : 0;
      A0 = *reinterpret_cast<const f16x8*>(wp + (size_t)tn * 2048);
      B0 = *reinterpret_cast<const f16x8*>(xp + (size_t)tn * 2048);
      const f32x16 pr =
          __builtin_amdgcn_mfma_f32_32x32x16_f16(a, b, z, 0, 0, 0);
      float d0 = pr[0] * cvr[0], d1 = pr[1] * cvr[1];
      float d2 = pr[2] * cvr[2], d3 = pr[3] * cvr[3];
#pragma unroll
      for (int r = 4; r < 16; r += 4) {
        d0 = fmaf(pr[r + 0], cvr[r + 0], d0);
        d1 = fmaf(pr[r + 1], cvr[r + 1], d1);
        d2 = fmaf(pr[r + 2], cvr[r + 2], d2);
        d3 = fmaf(pr[r + 3], cvr[r + 3], d3);
      }
      float dp = (d0 + d1) + (d2 + d3);
      dp += __shfl_xor(dp, 32);
      const float e = __expf(dp);
      lacc += e;
#pragma unroll
      for (int r = 0; r < 16; ++r) accA[r] = fmaf(e, pr[r], accA[r]);
    }
    // ---- tile t+1 (slot 1) ----
    {
      const f16x8 a = A1;
      const f16x8 b = B1;
      const int tn = (t + 3 < TILES) ? t + 3 : 0;
      A1 = *reinterpret_cast<const f16x8*>(wp + (size_t)tn * 2048);
      B1 = *reinterpret_cast<const f16x8*>(xp + (size_t)tn * 2048);
      const f32x16 pr =
          __builtin_amdgcn_mfma_f32_32x32x16_f16(a, b, z, 0, 0, 0);
      float d0 = pr[0] * cvr[0], d1 = pr[1] * cvr[1];
      float d2 = pr[2] * cvr[2], d3 = pr[3] * cvr[3];
#pragma unroll
      for (int r = 4; r < 16; r += 4) {
        d0 = fmaf(pr[r + 0], cvr[r + 0], d0);
        d1 = fmaf(pr[r + 1], cvr[r + 1], d1);
        d2 = fmaf(pr[r + 2], cvr[r + 2], d2);
        d3 = fmaf(pr[r + 3], cvr[r + 3], d3);
      }
      float dp = (d0 + d1) + (d2 + d3);
      dp += __shfl_xor(dp, 32);
      const float e = __expf(dp);
      lacc += e;
#pragma unroll
      for (int r = 0; r < 16; ++r) accB[r] = fmaf(e, pr[r], accB[r]);
    }
  }
#pragma unroll
  for (int r = 0; r < 16; ++r) accA[r] += accB[r];

#pragma unroll
  for (int r = 0; r < 16; ++r)
    red[w][(r & 3) + 8 * (r >> 2) + 4 * h][m] = accA[r];
  if (h == 0) lred[w][m] = lacc;
  __syncthreads();

  float* Pp = partials + ((size_t)c * CHUNKS + chunk) * PS;
#pragma unroll
  for (int e = tid; e < 1024; e += 256) {
    const int d = e >> 5, bb = e & 31;
    Pp[e] = red[0][d][bb] + red[1][d][bb] + red[2][d][bb] + red[3][d][bb];
  }
  if (tid < 32)
    Pp[1024 + tid] = lred[0][tid] + lred[1][tid] + lred[2][tid] + lred[3][tid];
}

// ---- reduce over chunks + squash (one block per c; R4-proven) ----
template <int K>
__global__ __launch_bounds__(1024) void k_reduce(
    const float* __restrict__ partials, float* __restrict__ CV,
    float* __restrict__ out) {
  const int c = blockIdx.x;
  const int t = threadIdx.x;  // t = b*32 + d (output layout)
  const int b = t >> 5, d = t & 31;
  const float* Pc = partials + (size_t)c * CHUNKS * PS;
  float s = 0.f;
#pragma unroll 4
  for (int ch = 0; ch < CHUNKS; ++ch) s += Pc[(size_t)ch * PS + d * 32 + b];
  float inv;
  if constexpr (K == 0) {
    inv = 1.0f / (float)kN;
  } else {
    float lb = 0.f;
#pragma unroll 4
    for (int ch = 0; ch < CHUNKS; ++ch) lb += Pc[(size_t)ch * PS + 1024 + b];
    inv = 1.0f / lb;
  }
  const float sv = s * inv;
  float sn = sv * sv;
  sn += __shfl_xor(sn, 1);
  sn += __shfl_xor(sn, 2);
  sn += __shfl_xor(sn, 4);
  sn += __shfl_xor(sn, 8);
  sn += __shfl_xor(sn, 16);  // |s|^2 over the 32 d's of this b
  const float coef = sqrtf(sn) / (1.0f + sn);
  const float o = sv * coef;  // squash
  if constexpr (K == 2)
    out[(size_t)c * 1024 + t] = o;
  else if constexpr (K == 0)
    CV[(size_t)c * 1024 + t] = o;
  else
    CV[(size_t)c * 1024 + t] += o;
}

// ---------------- v1 single-kernel fallback (no ws; passed @~590us) --------
namespace v1 {
constexpr int BG = 4, NSLOT = 128, THREADS1 = NSLOT * 8;
template <int MODE>
__device__ __forceinline__ void sweep_pass(const float* __restrict__ Wc,
                                           const float* __restrict__ x, int b0,
                                           int tid, int nslot, int dg,
                                           float (*red)[8][20], float (*sS)[kD],
                                           float* sL, const float (*sVec)[kD]) {
  float acc[BG][4];
  float lv[BG];
#pragma unroll
  for (int b = 0; b < BG; ++b) {
    lv[b] = 0.f;
#pragma unroll
    for (int j = 0; j < 4; ++j) acc[b][j] = 0.f;
  }
  float vec[BG][4];
  if (MODE) {
#pragma unroll
    for (int b = 0; b < BG; ++b)
#pragma unroll
      for (int j = 0; j < 4; ++j) vec[b][j] = sVec[b][4 * dg + j];
  }
#pragma unroll 1
  for (int n = nslot; n < kN; n += NSLOT) {
    const float* Wn = Wc + (size_t)n * (kI * kD) + 4 * dg;
    float pr[BG][4];
#pragma unroll
    for (int b = 0; b < BG; ++b)
#pragma unroll
      for (int j = 0; j < 4; ++j) pr[b][j] = 0.f;
#pragma unroll
    for (int iq = 0; iq < 4; ++iq) {
      float4 wv[4];
#pragma unroll
      for (int r = 0; r < 4; ++r)
        wv[r] = *reinterpret_cast<const float4*>(Wn + (4 * iq + r) * kD);
#pragma unroll
      for (int b = 0; b < BG; ++b) {
        const float4 xv = *reinterpret_cast<const float4*>(
            x + ((size_t)(b0 + b) * kN + n) * kI + 4 * iq);
        const float xsv[4] = {xv.x, xv.y, xv.z, xv.w};
#pragma unroll
        for (int r = 0; r < 4; ++r) {
          pr[b][0] = fmaf(xsv[r], wv[r].x, pr[b][0]);
          pr[b][1] = fmaf(xsv[r], wv[r].y, pr[b][1]);
          pr[b][2] = fmaf(xsv[r], wv[r].z, pr[b][2]);
          pr[b][3] = fmaf(xsv[r], wv[r].w, pr[b][3]);
        }
      }
    }
    if (MODE == 0) {
#pragma unroll
      for (int b = 0; b < BG; ++b)
#pragma unroll
        for (int j = 0; j < 4; ++j) acc[b][j] += pr[b][j];
    } else {
#pragma unroll
      for (int b = 0; b < BG; ++b) {
        float dp = pr[b][0] * vec[b][0] + pr[b][1] * vec[b][1] +
                   pr[b][2] * vec[b][2] + pr[b][3] * vec[b][3];
        dp += __shfl_xor(dp, 1);
        dp += __shfl_xor(dp, 2);
        dp += __shfl_xor(dp, 4);
        const float e = __expf(dp);
        lv[b] += e;
        acc[b][0] = fmaf(e, pr[b][0], acc[b][0]);
        acc[b][1] = fmaf(e, pr[b][1], acc[b][1]);
        acc[b][2] = fmaf(e, pr[b][2], acc[b][2]);
        acc[b][3] = fmaf(e, pr[b][3], acc[b][3]);
      }
    }
  }
#pragma unroll
  for (int b = 0; b < BG; ++b) {
#pragma unroll
    for (int j = 0; j < 4; ++j) {
      float v = acc[b][j];
      v += __shfl_xor(v, 8);
      v += __shfl_xor(v, 16);
      v += __shfl_xor(v, 32);
      acc[b][j] = v;
    }
    if (MODE) {
      float v = lv[b];
      v += __shfl_xor(v, 8);
      v += __shfl_xor(v, 16);
      v += __shfl_xor(v, 32);
      lv[b] = v;
    }
  }
  const int lane = tid & 63;
  const int wv_id = tid >> 6;
  if ((lane >> 3) == 0) {
#pragma unroll
    for (int b = 0; b < BG; ++b) {
#pragma unroll
      for (int j = 0; j < 4; ++j) red[wv_id][dg][4 * b + j] = acc[b][j];
      if (MODE) red[wv_id][dg][16 + b] = lv[b];
    }
  }
  __syncthreads();
  if (tid < 128) {
    const int dgc = tid >> 4, e = tid & 15;
    float s = 0.f;
#pragma unroll
    for (int w = 0; w < 16; ++w) s += red[w][dgc][e];
    sS[e >> 2][4 * dgc + (e & 3)] = s;
  }
  if (MODE && tid >= 128 && tid < 128 + BG) {
    const int b = tid - 128;
    float s = 0.f;
#pragma unroll
    for (int w = 0; w < 16; ++w) s += red[w][0][16 + b];
    sL[b] = s;
  }
  __syncthreads();
}

__global__ __launch_bounds__(THREADS1, 4) void caps_route_kernel(
    const float* __restrict__ x, const float* __restrict__ W,
    float* __restrict__ out) {
  __shared__ float red[16][8][20];
  __shared__ float sS[BG][kD];
  __shared__ float sVec[BG][kD];
  __shared__ float sL[BG];
  const int i = blockIdx.x;
  const int xcd = i & 7;
  const int j = i >> 3;
  const int c = xcd + 8 * (j >> 3);
  const int b0 = 4 * (j & 7);
  const int tid = threadIdx.x;
  const int nslot = tid >> 3;
  const int dg = tid & 7;
  const float* Wc = W + (size_t)c * kN * kI * kD;
  sweep_pass<0>(Wc, x, b0, tid, nslot, dg, red, sS, sL, sVec);
  if (tid < BG) {
    const int b = tid;
    float sval[kD], sn = 0.f;
    const float inv = 1.0f / (float)kN;
#pragma unroll
    for (int d = 0; d < kD; ++d) {
      sval[d] = sS[b][d] * inv;
      sn += sval[d] * sval[d];
    }
    const float coef = sqrtf(sn) / (1.0f + sn);
#pragma unroll
    for (int d = 0; d < kD; ++d) sVec[b][d] = sval[d] * coef;
  }
  __syncthreads();
  sweep_pass<1>(Wc, x, b0, tid, nslot, dg, red, sS, sL, sVec);
  if (tid < BG) {
    const int b = tid;
    float sval[kD], sn = 0.f;
    const float inv = 1.0f / sL[b];
#pragma unroll
    for (int d = 0; d < kD; ++d) {
      sval[d] = sS[b][d] * inv;
      sn += sval[d] * sval[d];
    }
    const float coef = sqrtf(sn) / (1.0f + sn);
#pragma unroll
    for (int d = 0; d < kD; ++d) sVec[b][d] += sval[d] * coef;
  }
  __syncthreads();
  sweep_pass<1>(Wc, x, b0, tid, nslot, dg, red, sS, sL, sVec);
  if (tid < BG) {
    const int b = tid;
    float sval[kD], sn = 0.f;
    const float inv = 1.0f / sL[b];
#pragma unroll
    for (int d = 0; d < kD; ++d) {
      sval[d] = sS[b][d] * inv;
      sn += sval[d] * sval[d];
    }
    const float coef = sqrtf(sn) / (1.0f + sn);
    float* o = out + ((size_t)c * kB + (b0 + b)) * kD;
#pragma unroll
    for (int d = 0; d < kD; ++d) o[d] = sval[d] * coef;
  }
}
}  // namespace v1

extern "C" void kernel_launch(void* const* d_in, const int* in_sizes, int n_in,
                              void* d_out, int out_size, void* d_ws,
                              size_t ws_size, hipStream_t stream) {
  const float* x = (const float*)d_in[0];  // [B,N,IN] fp32
  const float* W = (const float*)d_in[1];  // [C,N,IN,OUT] fp32
  float* out = (float*)d_out;              // [C,B,1,1,OUT] fp32
  (void)in_sizes; (void)n_in; (void)out_size;

  if (ws_size >= WS_BYTES_BIG) {
    _Float16* xt = (_Float16*)d_ws;
    _Float16* Wt = xt + XT_ELEMS;
    float* P = (float*)(Wt + WT_ELEMS);
    float* CV = P + P_FLOATS;

    k_xt<<<GRID, 256, 0, stream>>>(x, xt);
    k_sweep<0, true><<<GRID, 256, 0, stream>>>(W, xt, nullptr, P, Wt);
    k_reduce<0><<<kC, 1024, 0, stream>>>(P, CV, nullptr);
    k_sweep_wt<<<GRID, 256, 0, stream>>>(Wt, xt, CV, P);
    k_reduce<1><<<kC, 1024, 0, stream>>>(P, CV, nullptr);
    k_sweep_wt<<<GRID, 256, 0, stream>>>(Wt, xt, CV, P);
    k_reduce<2><<<kC, 1024, 0, stream>>>(P, nullptr, out);
    return;
  }

  if (ws_size >= WS_BYTES_MID) {
    _Float16* xt = (_Float16*)d_ws;
    float* P = (float*)(xt + XT_ELEMS);
    float* CV = P + P_FLOATS;

    k_xt<<<GRID, 256, 0, stream>>>(x, xt);
    k_sweep<0, false><<<GRID, 256, 0, stream>>>(W, xt, nullptr, P, nullptr);
    k_reduce<0><<<kC, 1024, 0, stream>>>(P, CV, nullptr);
    k_sweep<1, false><<<GRID, 256, 0, stream>>>(W, xt, CV, P, nullptr);
    k_reduce<1><<<kC, 1024, 0, stream>>>(P, CV, nullptr);
    k_sweep<1, false><<<GRID, 256, 0, stream>>>(W, xt, CV, P, nullptr);
    k_reduce<2><<<kC, 1024, 0, stream>>>(P, nullptr, out);
    return;
  }

  v1::caps_route_kernel<<<256, v1::THREADS1, 0, stream>>>(x, W, out);
}

// Round 2
// 200.911 us; speedup vs baseline: 1.0110x; 1.0004x over previous
//
#include <hip/hip_runtime.h>
#include <hip/hip_cooperative_groups.h>
#include <math.h>

namespace cg = cooperative_groups;

// CapsuleLayer dynamic routing. C=32,B=32,N=4096,IN=16,OUT=32, 3 iters.
// v10: single cooperative mega-kernel (post-xt). v9's null result (654 MB vs
// 768 MB byte budgets both ~201us) shows the chain is not byte-bound; the
// invariant across R4/v8/v9 is the 7-kernel serial structure. v10 removes 5
// kernel boundaries via grid.sync(), keeps Wt f16 fragments L3-resident
// across sweeps, and keeps numerics bit-identical to v9's sweep order.
// Coherence protocol (per-XCD L2s not cross-coherent): plain stores +
// __threadfence() (agent release = wbl2) + grid.sync(); consumers read
// FRESH addresses each phase (P0/P1/P2, CVa/CVb) so no stale L2 lines are
// possible (kernel-start acquire invalidated everything older).
// Fallbacks: v9 7-kernel path (proven 201us) if coop not possible; v1 if no ws.

typedef _Float16 f16x8 __attribute__((ext_vector_type(8)));
typedef float f32x16 __attribute__((ext_vector_type(16)));

namespace {
constexpr int kC = 32, kB = 32, kN = 4096, kI = 16, kD = 32;
constexpr int CHUNKS = 32;            // n-chunks per c
constexpr int CHUNK_N = kN / CHUNKS;  // 128
constexpr int PS = kB * kD + kB;      // 1056 floats per (c,chunk) partial
constexpr int GRID = kC * CHUNKS;     // 1024 blocks
constexpr size_t XT_ELEMS = (size_t)kN * kB * kI;       // f16 [n][b][i]
constexpr size_t WT_ELEMS = (size_t)kC * kN * kI * kD;  // f16 fragment layout
constexpr size_t P_FLOATS = (size_t)kC * CHUNKS * PS;
constexpr size_t CV_FLOATS = (size_t)kC * kB * kD;
constexpr size_t WS_BYTES_MID = XT_ELEMS * 2 + (P_FLOATS + CV_FLOATS) * 4;
constexpr size_t WS_BYTES_BIG =
    (XT_ELEMS + WT_ELEMS) * 2 + (P_FLOATS + CV_FLOATS) * 4;
constexpr size_t WS_BYTES_COOP =
    (XT_ELEMS + WT_ELEMS) * 2 + (3 * P_FLOATS + 2 * CV_FLOATS) * 4;
}  // namespace

__device__ __forceinline__ f32x16 zero16() {
  f32x16 z;
#pragma unroll
  for (int r = 0; r < 16; ++r) z[r] = 0.f;
  return z;
}

// ---- k_xt: x[b][n][i] f32 -> xt[n][b][i] f16 (1024 blocks, half-row/thr) --
__global__ __launch_bounds__(256) void k_xt(const float* __restrict__ x,
                                            _Float16* __restrict__ xt) {
  const int t = blockIdx.x * 256 + threadIdx.x;  // [0, 262144) == 2*B*N
  const int r = t >> 1, half = t & 1;            // r = b*4096 + n
  const int b = r >> 12, n = r & 4095;
  const float4* s4 =
      reinterpret_cast<const float4*>(x) + (size_t)r * 4 + half * 2;
  const float4 f0 = s4[0], f1 = s4[1];
  f16x8 o;
  o[0] = (_Float16)f0.x; o[1] = (_Float16)f0.y;
  o[2] = (_Float16)f0.z; o[3] = (_Float16)f0.w;
  o[4] = (_Float16)f1.x; o[5] = (_Float16)f1.y;
  o[6] = (_Float16)f1.z; o[7] = (_Float16)f1.w;
  *reinterpret_cast<f16x8*>(xt + ((size_t)n * kB + b) * kI + half * 8) = o;
}

// ================= mega-kernel phase bodies (device functions) =============

// Sweep 0: MODE 0 (uniform probs, acc in MFMA C) + EMIT Wt f16 fragments.
// Bitwise-identical accumulation order to v9's k_sweep<0,true>.
__device__ __forceinline__ void mega_sweep0(const float* __restrict__ W,
                                            const _Float16* __restrict__ xt,
                                            _Float16* __restrict__ Wt,
                                            float* __restrict__ P,
                                            float (*red)[32][33], int c,
                                            int chunk, int tid) {
  const int w = tid >> 6, l = tid & 63;
  const int m = l & 31, h = l >> 5;
  const int n0 = chunk * CHUNK_N;
  constexpr int TILES = CHUNK_N / 4;

  const float* wp = W + ((size_t)c * kN + n0 + w) * 512 + (h * 8) * 32 + m;
  const _Float16* xp = xt + ((size_t)(n0 + w)) * 512 + m * 16 + h * 8;
  _Float16* wtp = Wt + ((size_t)c * kN + n0 + w) * 512 + (size_t)l * 8;

  f32x16 accA = zero16(), accB = zero16();

  float rA0[8], rA1[8];
  f16x8 B0, B1;
#pragma unroll
  for (int j = 0; j < 8; ++j) rA0[j] = __builtin_nontemporal_load(wp + j * 32);
  B0 = *reinterpret_cast<const f16x8*>(xp);
#pragma unroll
  for (int j = 0; j < 8; ++j)
    rA1[j] = __builtin_nontemporal_load(wp + 2048 + j * 32);
  B1 = *reinterpret_cast<const f16x8*>(xp + 2048);

#pragma unroll 1
  for (int t = 0; t < TILES; t += 2) {
    {
      f16x8 a;
#pragma unroll
      for (int j = 0; j < 8; ++j) a[j] = (_Float16)rA0[j];
      const f16x8 b = B0;
      const int tn = (t + 2 < TILES) ? t + 2 : 0;
#pragma unroll
      for (int j = 0; j < 8; ++j)
        rA0[j] = __builtin_nontemporal_load(wp + (size_t)tn * 2048 + j * 32);
      B0 = *reinterpret_cast<const f16x8*>(xp + (size_t)tn * 2048);
      *reinterpret_cast<f16x8*>(wtp + (size_t)t * 2048) = a;
      accA = __builtin_amdgcn_mfma_f32_32x32x16_f16(a, b, accA, 0, 0, 0);
    }
    {
      f16x8 a;
#pragma unroll
      for (int j = 0; j < 8; ++j) a[j] = (_Float16)rA1[j];
      const f16x8 b = B1;
      const int tn = (t + 3 < TILES) ? t + 3 : 0;
#pragma unroll
      for (int j = 0; j < 8; ++j)
        rA1[j] = __builtin_nontemporal_load(wp + (size_t)tn * 2048 + j * 32);
      B1 = *reinterpret_cast<const f16x8*>(xp + (size_t)tn * 2048);
      *reinterpret_cast<f16x8*>(wtp + (size_t)(t + 1) * 2048) = a;
      accB = __builtin_amdgcn_mfma_f32_32x32x16_f16(a, b, accB, 0, 0, 0);
    }
  }
#pragma unroll
  for (int r = 0; r < 16; ++r) accA[r] += accB[r];

#pragma unroll
  for (int r = 0; r < 16; ++r)
    red[w][(r & 3) + 8 * (r >> 2) + 4 * h][m] = accA[r];
  __syncthreads();

  float* Pp = P + ((size_t)c * CHUNKS + chunk) * PS;
#pragma unroll
  for (int e = tid; e < 1024; e += 256) {
    const int d = e >> 5, bb = e & 31;
    Pp[e] = red[0][d][bb] + red[1][d][bb] + red[2][d][bb] + red[3][d][bb];
  }
  __syncthreads();  // red reused next phase
}

// MODE-1 sweep over Wt f16 fragments (identical numerics to v9 k_sweep_wt).
__device__ __forceinline__ void mega_sweep_wt(
    const _Float16* __restrict__ Wt, const _Float16* __restrict__ xt,
    const float* __restrict__ cumVec, float* __restrict__ P,
    float (*red)[32][33], float (*lred)[32], int c, int chunk, int tid) {
  const int w = tid >> 6, l = tid & 63;
  const int m = l & 31, h = l >> 5;
  const int n0 = chunk * CHUNK_N;
  constexpr int TILES = CHUNK_N / 4;

  const _Float16* wp = Wt + ((size_t)c * kN + n0 + w) * 512 + (size_t)l * 8;
  const _Float16* xp = xt + ((size_t)(n0 + w)) * 512 + m * 16 + h * 8;

  float cvr[16];
  const float* cvp = cumVec + (size_t)c * 1024 + m * 32;
#pragma unroll
  for (int r = 0; r < 16; ++r) cvr[r] = cvp[(r & 3) + 8 * (r >> 2) + 4 * h];

  f32x16 accA = zero16(), accB = zero16();
  float lacc = 0.f;
  const f32x16 z = zero16();

  f16x8 A0, A1, B0, B1;
  A0 = *reinterpret_cast<const f16x8*>(wp);
  B0 = *reinterpret_cast<const f16x8*>(xp);
  A1 = *reinterpret_cast<const f16x8*>(wp + 2048);
  B1 = *reinterpret_cast<const f16x8*>(xp + 2048);

#pragma unroll 1
  for (int t = 0; t < TILES; t += 2) {
    {
      const f16x8 a = A0;
      const f16x8 b = B0;
      const int tn = (t + 2 < TILES) ? t + 2 : 0;
      A0 = *reinterpret_cast<const f16x8*>(wp + (size_t)tn * 2048);
      B0 = *reinterpret_cast<const f16x8*>(xp + (size_t)tn * 2048);
      const f32x16 pr =
          __builtin_amdgcn_mfma_f32_32x32x16_f16(a, b, z, 0, 0, 0);
      float d0 = pr[0] * cvr[0], d1 = pr[1] * cvr[1];
      float d2 = pr[2] * cvr[2], d3 = pr[3] * cvr[3];
#pragma unroll
      for (int r = 4; r < 16; r += 4) {
        d0 = fmaf(pr[r + 0], cvr[r + 0], d0);
        d1 = fmaf(pr[r + 1], cvr[r + 1], d1);
        d2 = fmaf(pr[r + 2], cvr[r + 2], d2);
        d3 = fmaf(pr[r + 3], cvr[r + 3], d3);
      }
      float dp = (d0 + d1) + (d2 + d3);
      dp += __shfl_xor(dp, 32);
      const float e = __expf(dp);
      lacc += e;
#pragma unroll
      for (int r = 0; r < 16; ++r) accA[r] = fmaf(e, pr[r], accA[r]);
    }
    {
      const f16x8 a = A1;
      const f16x8 b = B1;
      const int tn = (t + 3 < TILES) ? t + 3 : 0;
      A1 = *reinterpret_cast<const f16x8*>(wp + (size_t)tn * 2048);
      B1 = *reinterpret_cast<const f16x8*>(xp + (size_t)tn * 2048);
      const f32x16 pr =
          __builtin_amdgcn_mfma_f32_32x32x16_f16(a, b, z, 0, 0, 0);
      float d0 = pr[0] * cvr[0], d1 = pr[1] * cvr[1];
      float d2 = pr[2] * cvr[2], d3 = pr[3] * cvr[3];
#pragma unroll
      for (int r = 4; r < 16; r += 4) {
        d0 = fmaf(pr[r + 0], cvr[r + 0], d0);
        d1 = fmaf(pr[r + 1], cvr[r + 1], d1);
        d2 = fmaf(pr[r + 2], cvr[r + 2], d2);
        d3 = fmaf(pr[r + 3], cvr[r + 3], d3);
      }
      float dp = (d0 + d1) + (d2 + d3);
      dp += __shfl_xor(dp, 32);
      const float e = __expf(dp);
      lacc += e;
#pragma unroll
      for (int r = 0; r < 16; ++r) accB[r] = fmaf(e, pr[r], accB[r]);
    }
  }
#pragma unroll
  for (int r = 0; r < 16; ++r) accA[r] += accB[r];

#pragma unroll
  for (int r = 0; r < 16; ++r)
    red[w][(r & 3) + 8 * (r >> 2) + 4 * h][m] = accA[r];
  if (h == 0) lred[w][m] = lacc;
  __syncthreads();

  float* Pp = P + ((size_t)c * CHUNKS + chunk) * PS;
#pragma unroll
  for (int e = tid; e < 1024; e += 256) {
    const int d = e >> 5, bb = e & 31;
    Pp[e] = red[0][d][bb] + red[1][d][bb] + red[2][d][bb] + red[3][d][bb];
  }
  if (tid < 32)
    Pp[1024 + tid] = lred[0][tid] + lred[1][tid] + lred[2][tid] + lred[3][tid];
  __syncthreads();  // red/lred reused next phase
}

// Reduce over chunks + squash, 256-thread version. Block c<32 only.
// t: b = t>>3 (32 b), dg = t&7 owns d = dg + 8k, k<4. cvrun carried in regs.
template <int K>
__device__ __forceinline__ void mega_reduce(const float* __restrict__ P,
                                            float* __restrict__ CVout,
                                            float* __restrict__ out,
                                            float (&cvrun)[4], int c, int t) {
  const int b = t >> 3, dg = t & 7;
  const float* Pc = P + (size_t)c * CHUNKS * PS;
  float s0 = 0.f, s1 = 0.f, s2 = 0.f, s3 = 0.f, lb = 0.f;
#pragma unroll 4
  for (int ch = 0; ch < CHUNKS; ++ch) {
    const float* base = Pc + (size_t)ch * PS;
    s0 += base[(dg + 0) * 32 + b];
    s1 += base[(dg + 8) * 32 + b];
    s2 += base[(dg + 16) * 32 + b];
    s3 += base[(dg + 24) * 32 + b];
    if (K != 0 && dg == 0) lb += base[1024 + b];
  }
  float inv;
  if constexpr (K == 0) {
    inv = 1.0f / (float)kN;
  } else {
    lb = __shfl(lb, (t & 63) & 56);  // broadcast from dg==0 lane of b-group
    inv = 1.0f / lb;
  }
  const float v0 = s0 * inv, v1 = s1 * inv, v2 = s2 * inv, v3 = s3 * inv;
  float sn = v0 * v0 + v1 * v1 + v2 * v2 + v3 * v3;
  sn += __shfl_xor(sn, 1);
  sn += __shfl_xor(sn, 2);
  sn += __shfl_xor(sn, 4);  // |s|^2 over all 32 d of this b
  const float coef = sqrtf(sn) / (1.0f + sn);
  const size_t o0 = (size_t)c * 1024 + b * 32 + dg;
  if constexpr (K == 0) {
    cvrun[0] = v0 * coef; cvrun[1] = v1 * coef;
    cvrun[2] = v2 * coef; cvrun[3] = v3 * coef;
    CVout[o0 + 0] = cvrun[0];  CVout[o0 + 8] = cvrun[1];
    CVout[o0 + 16] = cvrun[2]; CVout[o0 + 24] = cvrun[3];
  } else if constexpr (K == 1) {
    cvrun[0] += v0 * coef; cvrun[1] += v1 * coef;
    cvrun[2] += v2 * coef; cvrun[3] += v3 * coef;
    CVout[o0 + 0] = cvrun[0];  CVout[o0 + 8] = cvrun[1];
    CVout[o0 + 16] = cvrun[2]; CVout[o0 + 24] = cvrun[3];
  } else {
    out[o0 + 0] = v0 * coef;  out[o0 + 8] = v1 * coef;
    out[o0 + 16] = v2 * coef; out[o0 + 24] = v3 * coef;
  }
}

__global__ __launch_bounds__(256, 4) void k_mega(
    const float* __restrict__ W, const _Float16* __restrict__ xt,
    _Float16* __restrict__ Wt, float* __restrict__ P0, float* __restrict__ P1,
    float* __restrict__ P2, float* __restrict__ CVa, float* __restrict__ CVb,
    float* __restrict__ out) {
  __shared__ float red[4][32][33];
  __shared__ float lred[4][32];
  cg::grid_group grid = cg::this_grid();
  const int bid = blockIdx.x;
  const int c = bid & 31;  // same-c blocks on one XCD
  const int chunk = bid >> 5;
  const int tid = threadIdx.x;
  float cvrun[4] = {0.f, 0.f, 0.f, 0.f};

  mega_sweep0(W, xt, Wt, P0, red, c, chunk, tid);
  __threadfence();
  grid.sync();

  if (bid < 32) mega_reduce<0>(P0, CVa, nullptr, cvrun, bid, tid);
  __threadfence();
  grid.sync();

  mega_sweep_wt(Wt, xt, CVa, P1, red, lred, c, chunk, tid);
  __threadfence();
  grid.sync();

  if (bid < 32) mega_reduce<1>(P1, CVb, nullptr, cvrun, bid, tid);
  __threadfence();
  grid.sync();

  mega_sweep_wt(Wt, xt, CVb, P2, red, lred, c, chunk, tid);
  __threadfence();
  grid.sync();

  if (bid < 32) mega_reduce<2>(P2, nullptr, out, cvrun, bid, tid);
}

// ================= v9 fallback kernels (proven 201us) ======================

template <int MODE, bool EMIT>
__global__ __launch_bounds__(256) void k_sweep(const float* __restrict__ W,
                                               const _Float16* __restrict__ xt,
                                               const float* __restrict__ cumVec,
                                               float* __restrict__ partials,
                                               _Float16* __restrict__ Wt) {
  __shared__ float red[4][32][33];
  __shared__ float lred[4][32];
  const int bid = blockIdx.x;
  const int c = bid & 31;
  const int chunk = bid >> 5;
  const int tid = threadIdx.x;
  const int w = tid >> 6, l = tid & 63;
  const int m = l & 31, h = l >> 5;
  const int n0 = chunk * CHUNK_N;
  constexpr int TILES = CHUNK_N / 4;

  const float* wp = W + ((size_t)c * kN + n0 + w) * 512 + (h * 8) * 32 + m;
  const _Float16* xp = xt + ((size_t)(n0 + w)) * 512 + m * 16 + h * 8;
  _Float16* wtp =
      EMIT ? (Wt + ((size_t)c * kN + n0 + w) * 512 + (size_t)l * 8) : nullptr;

  float cvr[16];
  if (MODE) {
    const float* cvp = cumVec + (size_t)c * 1024 + m * 32;
#pragma unroll
    for (int r = 0; r < 16; ++r) cvr[r] = cvp[(r & 3) + 8 * (r >> 2) + 4 * h];
  }

  f32x16 accA = zero16(), accB = zero16();
  float lacc = 0.f;
  const f32x16 z = zero16();

  float rA0[8], rA1[8];
  f16x8 B0, B1;
#pragma unroll
  for (int j = 0; j < 8; ++j)
    rA0[j] = EMIT ? __builtin_nontemporal_load(wp + j * 32) : wp[j * 32];
  B0 = *reinterpret_cast<const f16x8*>(xp);
#pragma unroll
  for (int j = 0; j < 8; ++j)
    rA1[j] = EMIT ? __builtin_nontemporal_load(wp + 2048 + j * 32)
                  : wp[2048 + j * 32];
  B1 = *reinterpret_cast<const f16x8*>(xp + 2048);

#pragma unroll 1
  for (int t = 0; t < TILES; t += 2) {
    {
      f16x8 a;
#pragma unroll
      for (int j = 0; j < 8; ++j) a[j] = (_Float16)rA0[j];
      const f16x8 b = B0;
      const int tn = (t + 2 < TILES) ? t + 2 : 0;
#pragma unroll
      for (int j = 0; j < 8; ++j)
        rA0[j] = EMIT ? __builtin_nontemporal_load(wp + (size_t)tn * 2048 +
                                                   j * 32)
                      : wp[(size_t)tn * 2048 + j * 32];
      B0 = *reinterpret_cast<const f16x8*>(xp + (size_t)tn * 2048);
      if constexpr (EMIT)
        *reinterpret_cast<f16x8*>(wtp + (size_t)t * 2048) = a;
      if constexpr (MODE == 0) {
        accA = __builtin_amdgcn_mfma_f32_32x32x16_f16(a, b, accA, 0, 0, 0);
      } else {
        const f32x16 pr =
            __builtin_amdgcn_mfma_f32_32x32x16_f16(a, b, z, 0, 0, 0);
        float d0 = pr[0] * cvr[0], d1 = pr[1] * cvr[1];
        float d2 = pr[2] * cvr[2], d3 = pr[3] * cvr[3];
#pragma unroll
        for (int r = 4; r < 16; r += 4) {
          d0 = fmaf(pr[r + 0], cvr[r + 0], d0);
          d1 = fmaf(pr[r + 1], cvr[r + 1], d1);
          d2 = fmaf(pr[r + 2], cvr[r + 2], d2);
          d3 = fmaf(pr[r + 3], cvr[r + 3], d3);
        }
        float dp = (d0 + d1) + (d2 + d3);
        dp += __shfl_xor(dp, 32);
        const float e = __expf(dp);
        lacc += e;
#pragma unroll
        for (int r = 0; r < 16; ++r) accA[r] = fmaf(e, pr[r], accA[r]);
      }
    }
    {
      f16x8 a;
#pragma unroll
      for (int j = 0; j < 8; ++j) a[j] = (_Float16)rA1[j];
      const f16x8 b = B1;
      const int tn = (t + 3 < TILES) ? t + 3 : 0;
#pragma unroll
      for (int j = 0; j < 8; ++j)
        rA1[j] = EMIT ? __builtin_nontemporal_load(wp + (size_t)tn * 2048 +
                                                   j * 32)
                      : wp[(size_t)tn * 2048 + j * 32];
      B1 = *reinterpret_cast<const f16x8*>(xp + (size_t)tn * 2048);
      if constexpr (EMIT)
        *reinterpret_cast<f16x8*>(wtp + (size_t)(t + 1) * 2048) = a;
      if constexpr (MODE == 0) {
        accB = __builtin_amdgcn_mfma_f32_32x32x16_f16(a, b, accB, 0, 0, 0);
      } else {
        const f32x16 pr =
            __builtin_amdgcn_mfma_f32_32x32x16_f16(a, b, z, 0, 0, 0);
        float d0 = pr[0] * cvr[0], d1 = pr[1] * cvr[1];
        float d2 = pr[2] * cvr[2], d3 = pr[3] * cvr[3];
#pragma unroll
        for (int r = 4; r < 16; r += 4) {
          d0 = fmaf(pr[r + 0], cvr[r + 0], d0);
          d1 = fmaf(pr[r + 1], cvr[r + 1], d1);
          d2 = fmaf(pr[r + 2], cvr[r + 2], d2);
          d3 = fmaf(pr[r + 3], cvr[r + 3], d3);
        }
        float dp = (d0 + d1) + (d2 + d3);
        dp += __shfl_xor(dp, 32);
        const float e = __expf(dp);
        lacc += e;
#pragma unroll
        for (int r = 0; r < 16; ++r) accB[r] = fmaf(e, pr[r], accB[r]);
      }
    }
  }
#pragma unroll
  for (int r = 0; r < 16; ++r) accA[r] += accB[r];

#pragma unroll
  for (int r = 0; r < 16; ++r)
    red[w][(r & 3) + 8 * (r >> 2) + 4 * h][m] = accA[r];
  if (MODE && h == 0) lred[w][m] = lacc;
  __syncthreads();

  float* Pp = partials + ((size_t)c * CHUNKS + chunk) * PS;
#pragma unroll
  for (int e = tid; e < 1024; e += 256) {
    const int d = e >> 5, bb = e & 31;
    Pp[e] = red[0][d][bb] + red[1][d][bb] + red[2][d][bb] + red[3][d][bb];
  }
  if (MODE && tid < 32)
    Pp[1024 + tid] = lred[0][tid] + lred[1][tid] + lred[2][tid] + lred[3][tid];
}

__global__ __launch_bounds__(256) void k_sweep_wt(
    const _Float16* __restrict__ Wt, const _Float16* __restrict__ xt,
    const float* __restrict__ cumVec, float* __restrict__ partials) {
  __shared__ float red[4][32][33];
  __shared__ float lred[4][32];
  const int bid = blockIdx.x;
  const int c = bid & 31;
  const int chunk = bid >> 5;
  const int tid = threadIdx.x;
  mega_sweep_wt(Wt, xt, cumVec, partials, red, lred, c, chunk, tid);
}

template <int K>
__global__ __launch_bounds__(1024) void k_reduce(
    const float* __restrict__ partials, float* __restrict__ CV,
    float* __restrict__ out) {
  const int c = blockIdx.x;
  const int t = threadIdx.x;
  const int b = t >> 5, d = t & 31;
  const float* Pc = partials + (size_t)c * CHUNKS * PS;
  float s = 0.f;
#pragma unroll 4
  for (int ch = 0; ch < CHUNKS; ++ch) s += Pc[(size_t)ch * PS + d * 32 + b];
  float inv;
  if constexpr (K == 0) {
    inv = 1.0f / (float)kN;
  } else {
    float lb = 0.f;
#pragma unroll 4
    for (int ch = 0; ch < CHUNKS; ++ch) lb += Pc[(size_t)ch * PS + 1024 + b];
    inv = 1.0f / lb;
  }
  const float sv = s * inv;
  float sn = sv * sv;
  sn += __shfl_xor(sn, 1);
  sn += __shfl_xor(sn, 2);
  sn += __shfl_xor(sn, 4);
  sn += __shfl_xor(sn, 8);
  sn += __shfl_xor(sn, 16);
  const float coef = sqrtf(sn) / (1.0f + sn);
  const float o = sv * coef;
  if constexpr (K == 2)
    out[(size_t)c * 1024 + t] = o;
  else if constexpr (K == 0)
    CV[(size_t)c * 1024 + t] = o;
  else
    CV[(size_t)c * 1024 + t] += o;
}

// ---------------- v1 single-kernel fallback (no ws; passed @~590us) --------
namespace v1 {
constexpr int BG = 4, NSLOT = 128, THREADS1 = NSLOT * 8;
template <int MODE>
__device__ __forceinline__ void sweep_pass(const float* __restrict__ Wc,
                                           const float* __restrict__ x, int b0,
                                           int tid, int nslot, int dg,
                                           float (*red)[8][20], float (*sS)[kD],
                                           float* sL, const float (*sVec)[kD]) {
  float acc[BG][4];
  float lv[BG];
#pragma unroll
  for (int b = 0; b < BG; ++b) {
    lv[b] = 0.f;
#pragma unroll
    for (int j = 0; j < 4; ++j) acc[b][j] = 0.f;
  }
  float vec[BG][4];
  if (MODE) {
#pragma unroll
    for (int b = 0; b < BG; ++b)
#pragma unroll
      for (int j = 0; j < 4; ++j) vec[b][j] = sVec[b][4 * dg + j];
  }
#pragma unroll 1
  for (int n = nslot; n < kN; n += NSLOT) {
    const float* Wn = Wc + (size_t)n * (kI * kD) + 4 * dg;
    float pr[BG][4];
#pragma unroll
    for (int b = 0; b < BG; ++b)
#pragma unroll
      for (int j = 0; j < 4; ++j) pr[b][j] = 0.f;
#pragma unroll
    for (int iq = 0; iq < 4; ++iq) {
      float4 wv[4];
#pragma unroll
      for (int r = 0; r < 4; ++r)
        wv[r] = *reinterpret_cast<const float4*>(Wn + (4 * iq + r) * kD);
#pragma unroll
      for (int b = 0; b < BG; ++b) {
        const float4 xv = *reinterpret_cast<const float4*>(
            x + ((size_t)(b0 + b) * kN + n) * kI + 4 * iq);
        const float xsv[4] = {xv.x, xv.y, xv.z, xv.w};
#pragma unroll
        for (int r = 0; r < 4; ++r) {
          pr[b][0] = fmaf(xsv[r], wv[r].x, pr[b][0]);
          pr[b][1] = fmaf(xsv[r], wv[r].y, pr[b][1]);
          pr[b][2] = fmaf(xsv[r], wv[r].z, pr[b][2]);
          pr[b][3] = fmaf(xsv[r], wv[r].w, pr[b][3]);
        }
      }
    }
    if (MODE == 0) {
#pragma unroll
      for (int b = 0; b < BG; ++b)
#pragma unroll
        for (int j = 0; j < 4; ++j) acc[b][j] += pr[b][j];
    } else {
#pragma unroll
      for (int b = 0; b < BG; ++b) {
        float dp = pr[b][0] * vec[b][0] + pr[b][1] * vec[b][1] +
                   pr[b][2] * vec[b][2] + pr[b][3] * vec[b][3];
        dp += __shfl_xor(dp, 1);
        dp += __shfl_xor(dp, 2);
        dp += __shfl_xor(dp, 4);
        const float e = __expf(dp);
        lv[b] += e;
        acc[b][0] = fmaf(e, pr[b][0], acc[b][0]);
        acc[b][1] = fmaf(e, pr[b][1], acc[b][1]);
        acc[b][2] = fmaf(e, pr[b][2], acc[b][2]);
        acc[b][3] = fmaf(e, pr[b][3], acc[b][3]);
      }
    }
  }
#pragma unroll
  for (int b = 0; b < BG; ++b) {
#pragma unroll
    for (int j = 0; j < 4; ++j) {
      float v = acc[b][j];
      v += __shfl_xor(v, 8);
      v += __shfl_xor(v, 16);
      v += __shfl_xor(v, 32);
      acc[b][j] = v;
    }
    if (MODE) {
      float v = lv[b];
      v += __shfl_xor(v, 8);
      v += __shfl_xor(v, 16);
      v += __shfl_xor(v, 32);
      lv[b] = v;
    }
  }
  const int lane = tid & 63;
  const int wv_id = tid >> 6;
  if ((lane >> 3) == 0) {
#pragma unroll
    for (int b = 0; b < BG; ++b) {
#pragma unroll
      for (int j = 0; j < 4; ++j) red[wv_id][dg][4 * b + j] = acc[b][j];
      if (MODE) red[wv_id][dg][16 + b] = lv[b];
    }
  }
  __syncthreads();
  if (tid < 128) {
    const int dgc = tid >> 4, e = tid & 15;
    float s = 0.f;
#pragma unroll
    for (int w = 0; w < 16; ++w) s += red[w][dgc][e];
    sS[e >> 2][4 * dgc + (e & 3)] = s;
  }
  if (MODE && tid >= 128 && tid < 128 + BG) {
    const int b = tid - 128;
    float s = 0.f;
#pragma unroll
    for (int w = 0; w < 16; ++w) s += red[w][0][16 + b];
    sL[b] = s;
  }
  __syncthreads();
}

__global__ __launch_bounds__(THREADS1, 4) void caps_route_kernel(
    const float* __restrict__ x, const float* __restrict__ W,
    float* __restrict__ out) {
  __shared__ float red[16][8][20];
  __shared__ float sS[BG][kD];
  __shared__ float sVec[BG][kD];
  __shared__ float sL[BG];
  const int i = blockIdx.x;
  const int xcd = i & 7;
  const int j = i >> 3;
  const int c = xcd + 8 * (j >> 3);
  const int b0 = 4 * (j & 7);
  const int tid = threadIdx.x;
  const int nslot = tid >> 3;
  const int dg = tid & 7;
  const float* Wc = W + (size_t)c * kN * kI * kD;
  sweep_pass<0>(Wc, x, b0, tid, nslot, dg, red, sS, sL, sVec);
  if (tid < BG) {
    const int b = tid;
    float sval[kD], sn = 0.f;
    const float inv = 1.0f / (float)kN;
#pragma unroll
    for (int d = 0; d < kD; ++d) {
      sval[d] = sS[b][d] * inv;
      sn += sval[d] * sval[d];
    }
    const float coef = sqrtf(sn) / (1.0f + sn);
#pragma unroll
    for (int d = 0; d < kD; ++d) sVec[b][d] = sval[d] * coef;
  }
  __syncthreads();
  sweep_pass<1>(Wc, x, b0, tid, nslot, dg, red, sS, sL, sVec);
  if (tid < BG) {
    const int b = tid;
    float sval[kD], sn = 0.f;
    const float inv = 1.0f / sL[b];
#pragma unroll
    for (int d = 0; d < kD; ++d) {
      sval[d] = sS[b][d] * inv;
      sn += sval[d] * sval[d];
    }
    const float coef = sqrtf(sn) / (1.0f + sn);
#pragma unroll
    for (int d = 0; d < kD; ++d) sVec[b][d] += sval[d] * coef;
  }
  __syncthreads();
  sweep_pass<1>(Wc, x, b0, tid, nslot, dg, red, sS, sL, sVec);
  if (tid < BG) {
    const int b = tid;
    float sval[kD], sn = 0.f;
    const float inv = 1.0f / sL[b];
#pragma unroll
    for (int d = 0; d < kD; ++d) {
      sval[d] = sS[b][d] * inv;
      sn += sval[d] * sval[d];
    }
    const float coef = sqrtf(sn) / (1.0f + sn);
    float* o = out + ((size_t)c * kB + (b0 + b)) * kD;
#pragma unroll
    for (int d = 0; d < kD; ++d) o[d] = sval[d] * coef;
  }
}
}  // namespace v1

extern "C" void kernel_launch(void* const* d_in, const int* in_sizes, int n_in,
                              void* d_out, int out_size, void* d_ws,
                              size_t ws_size, hipStream_t stream) {
  const float* x = (const float*)d_in[0];  // [B,N,IN] fp32
  const float* W = (const float*)d_in[1];  // [C,N,IN,OUT] fp32
  float* out = (float*)d_out;              // [C,B,1,1,OUT] fp32
  (void)in_sizes; (void)n_in; (void)out_size;

  // One-time cooperative-capability check (host queries only; graph-safe).
  static int s_coop = -1;
  if (s_coop < 0) {
    int dev = 0;
    (void)hipGetDevice(&dev);
    int nCU = 0;
    (void)hipDeviceGetAttribute(&nCU, hipDeviceAttributeMultiprocessorCount,
                                dev);
    int maxB = 0;
    (void)hipOccupancyMaxActiveBlocksPerMultiprocessor(&maxB, k_mega, 256, 0);
    s_coop = (nCU > 0 && maxB > 0 && (size_t)nCU * maxB >= (size_t)GRID) ? 1
                                                                         : 0;
  }

  if (s_coop == 1 && ws_size >= WS_BYTES_COOP) {
    _Float16* xt = (_Float16*)d_ws;
    _Float16* Wt = xt + XT_ELEMS;
    float* P0 = (float*)(Wt + WT_ELEMS);
    float* P1 = P0 + P_FLOATS;
    float* P2 = P1 + P_FLOATS;
    float* CVa = P2 + P_FLOATS;
    float* CVb = CVa + CV_FLOATS;

    k_xt<<<GRID, 256, 0, stream>>>(x, xt);
    void* args[] = {(void*)&W,  (void*)&xt,  (void*)&Wt,
                    (void*)&P0, (void*)&P1,  (void*)&P2,
                    (void*)&CVa, (void*)&CVb, (void*)&out};
    if (hipLaunchCooperativeKernel(k_mega, dim3(GRID), dim3(256), args, 0,
                                   stream) == hipSuccess)
      return;
    // fall through to the 7-kernel path on launch failure (xt rebuild is
    // harmless: same data).
  }

  if (ws_size >= WS_BYTES_BIG) {
    _Float16* xt = (_Float16*)d_ws;
    _Float16* Wt = xt + XT_ELEMS;
    float* P = (float*)(Wt + WT_ELEMS);
    float* CV = P + P_FLOATS;

    k_xt<<<GRID, 256, 0, stream>>>(x, xt);
    k_sweep<0, true><<<GRID, 256, 0, stream>>>(W, xt, nullptr, P, Wt);
    k_reduce<0><<<kC, 1024, 0, stream>>>(P, CV, nullptr);
    k_sweep_wt<<<GRID, 256, 0, stream>>>(Wt, xt, CV, P);
    k_reduce<1><<<kC, 1024, 0, stream>>>(P, CV, nullptr);
    k_sweep_wt<<<GRID, 256, 0, stream>>>(Wt, xt, CV, P);
    k_reduce<2><<<kC, 1024, 0, stream>>>(P, nullptr, out);
    return;
  }

  if (ws_size >= WS_BYTES_MID) {
    _Float16* xt = (_Float16*)d_ws;
    float* P = (float*)(xt + XT_ELEMS);
    float* CV = P + P_FLOATS;

    k_xt<<<GRID, 256, 0, stream>>>(x, xt);
    k_sweep<0, false><<<GRID, 256, 0, stream>>>(W, xt, nullptr, P, nullptr);
    k_reduce<0><<<kC, 1024, 0, stream>>>(P, CV, nullptr);
    k_sweep<1, false><<<GRID, 256, 0, stream>>>(W, xt, CV, P, nullptr);
    k_reduce<1><<<kC, 1024, 0, stream>>>(P, CV, nullptr);
    k_sweep<1, false><<<GRID, 256, 0, stream>>>(W, xt, CV, P, nullptr);
    k_reduce<2><<<kC, 1024, 0, stream>>>(P, nullptr, out);
    return;
  }

  v1::caps_route_kernel<<<256, v1::THREADS1, 0, stream>>>(x, W, out);
}

// Round 3
// 200.693 us; speedup vs baseline: 1.0120x; 1.0011x over previous
//
#include <hip/hip_runtime.h>
#include <math.h>

// CapsuleLayer dynamic routing. C=32,B=32,N=4096,IN=16,OUT=32, 3 iters.
// v11: fused persistent kernel with CUSTOM grid barrier (plain launch).
// v10 diagnosis: (a) hipLaunchCooperativeKernel is not graph-capturable ->
// timed path silently ran v9 (200.9us == v9's 201); (b) rocprof'd mega ran
// 1200us with VALUBusy 2%, FETCH/WRITE exactly at the no-spill byte model ->
// cg::grid.sync() (~200us each x5) was the cost, not spills, not compute.
// v11: 2-level epoch barrier (32 c-group counters -> root, agent-scope
// atomics, threadfence release, s_sleep spin) ~1-2us each; only 3 barriers:
// reduce is computed redundantly per-block (agent-scope loads of P, ~135KB
// per block from L3) so CV lives in regs/LDS and needs no global sync.
// Distinct P0/P1/P2 per phase (no stale-line hazard); Wt written+read by the
// SAME block (plain L2 ops). Co-residency: __launch_bounds__(256,4) (v10
// codegen: 64 arch VGPR + AGPR acc, no spill) + host occupancy gate; else
// fall back to the proven v9 7-kernel path (201us), else v1.

typedef _Float16 f16x8 __attribute__((ext_vector_type(8)));
typedef float f32x16 __attribute__((ext_vector_type(16)));

namespace {
constexpr int kC = 32, kB = 32, kN = 4096, kI = 16, kD = 32;
constexpr int CHUNKS = 32;            // n-chunks per c
constexpr int CHUNK_N = kN / CHUNKS;  // 128
constexpr int PS = kB * kD + kB;      // 1056 floats per (c,chunk) partial
constexpr int GRID = kC * CHUNKS;     // 1024 blocks
constexpr size_t XT_ELEMS = (size_t)kN * kB * kI;       // f16 [n][b][i]
constexpr size_t WT_ELEMS = (size_t)kC * kN * kI * kD;  // f16 fragment layout
constexpr size_t P_FLOATS = (size_t)kC * CHUNKS * PS;
constexpr size_t CV_FLOATS = (size_t)kC * kB * kD;
constexpr int BAR_U32 = 33;  // [0..31] per-c group counters, [32] root
constexpr size_t WS_BYTES_MID = XT_ELEMS * 2 + (P_FLOATS + CV_FLOATS) * 4;
constexpr size_t WS_BYTES_BIG =
    (XT_ELEMS + WT_ELEMS) * 2 + (P_FLOATS + CV_FLOATS) * 4;
constexpr size_t WS_BYTES_MEGA =
    (XT_ELEMS + WT_ELEMS) * 2 + 3 * P_FLOATS * 4 + 256;
}  // namespace

__device__ __forceinline__ f32x16 zero16() {
  f32x16 z;
#pragma unroll
  for (int r = 0; r < 16; ++r) z[r] = 0.f;
  return z;
}

// ---- k_xt: x[b][n][i] f32 -> xt[n][b][i] f16; also zeroes barrier ctrs ----
__global__ __launch_bounds__(256) void k_xt(const float* __restrict__ x,
                                            _Float16* __restrict__ xt,
                                            unsigned* __restrict__ bar) {
  if (bar && blockIdx.x == 0 && threadIdx.x < BAR_U32) bar[threadIdx.x] = 0u;
  const int t = blockIdx.x * 256 + threadIdx.x;  // [0, 262144) == 2*B*N
  const int r = t >> 1, half = t & 1;            // r = b*4096 + n
  const int b = r >> 12, n = r & 4095;
  const float4* s4 =
      reinterpret_cast<const float4*>(x) + (size_t)r * 4 + half * 2;
  const float4 f0 = s4[0], f1 = s4[1];
  f16x8 o;
  o[0] = (_Float16)f0.x; o[1] = (_Float16)f0.y;
  o[2] = (_Float16)f0.z; o[3] = (_Float16)f0.w;
  o[4] = (_Float16)f1.x; o[5] = (_Float16)f1.y;
  o[6] = (_Float16)f1.z; o[7] = (_Float16)f1.w;
  *reinterpret_cast<f16x8*>(xt + ((size_t)n * kB + b) * kI + half * 8) = o;
}

// ---- custom grid barrier: 2-level, epoch-based, agent scope ---------------
// arrive: release own block's stores; last of the 32 same-c blocks bumps root.
// wait: spin until root >= 32*epoch.
__device__ __forceinline__ void bar_arrive(unsigned* bar, int bid, int tid) {
  __threadfence();   // wbl2: publish this block's plain stores to agent scope
  __syncthreads();   // all threads of block fenced
  if (tid == 0) {
    const int g = bid & 31;
    unsigned v = __hip_atomic_fetch_add(&bar[g], 1u, __ATOMIC_ACQ_REL,
                                        __HIP_MEMORY_SCOPE_AGENT);
    if ((v & 31u) == 31u)
      __hip_atomic_fetch_add(&bar[32], 1u, __ATOMIC_ACQ_REL,
                             __HIP_MEMORY_SCOPE_AGENT);
  }
}

__device__ __forceinline__ void bar_wait(unsigned* bar, int tid, int epoch) {
  if (tid == 0) {
    const unsigned target = 32u * (unsigned)epoch;
    while (__hip_atomic_load(&bar[32], __ATOMIC_ACQUIRE,
                             __HIP_MEMORY_SCOPE_AGENT) < target)
      __builtin_amdgcn_s_sleep(2);
  }
  __syncthreads();
}

// ================= fused-kernel phase bodies ===============================

// Sweep 0: MODE 0 (uniform probs, acc in MFMA C) + EMIT Wt f16 fragments.
__device__ __forceinline__ void mega_sweep0(const float* __restrict__ W,
                                            const _Float16* __restrict__ xt,
                                            _Float16* __restrict__ Wt,
                                            float* __restrict__ P,
                                            float (*red)[32][33], int c,
                                            int chunk, int tid) {
  const int w = tid >> 6, l = tid & 63;
  const int m = l & 31, h = l >> 5;
  const int n0 = chunk * CHUNK_N;
  constexpr int TILES = CHUNK_N / 4;

  const float* wp = W + ((size_t)c * kN + n0 + w) * 512 + (h * 8) * 32 + m;
  const _Float16* xp = xt + ((size_t)(n0 + w)) * 512 + m * 16 + h * 8;
  _Float16* wtp = Wt + ((size_t)c * kN + n0 + w) * 512 + (size_t)l * 8;

  f32x16 accA = zero16(), accB = zero16();

  float rA0[8], rA1[8];
  f16x8 B0, B1;
#pragma unroll
  for (int j = 0; j < 8; ++j) rA0[j] = __builtin_nontemporal_load(wp + j * 32);
  B0 = *reinterpret_cast<const f16x8*>(xp);
#pragma unroll
  for (int j = 0; j < 8; ++j)
    rA1[j] = __builtin_nontemporal_load(wp + 2048 + j * 32);
  B1 = *reinterpret_cast<const f16x8*>(xp + 2048);

#pragma unroll 1
  for (int t = 0; t < TILES; t += 2) {
    {
      f16x8 a;
#pragma unroll
      for (int j = 0; j < 8; ++j) a[j] = (_Float16)rA0[j];
      const f16x8 b = B0;
      const int tn = (t + 2 < TILES) ? t + 2 : 0;
#pragma unroll
      for (int j = 0; j < 8; ++j)
        rA0[j] = __builtin_nontemporal_load(wp + (size_t)tn * 2048 + j * 32);
      B0 = *reinterpret_cast<const f16x8*>(xp + (size_t)tn * 2048);
      *reinterpret_cast<f16x8*>(wtp + (size_t)t * 2048) = a;
      accA = __builtin_amdgcn_mfma_f32_32x32x16_f16(a, b, accA, 0, 0, 0);
    }
    {
      f16x8 a;
#pragma unroll
      for (int j = 0; j < 8; ++j) a[j] = (_Float16)rA1[j];
      const f16x8 b = B1;
      const int tn = (t + 3 < TILES) ? t + 3 : 0;
#pragma unroll
      for (int j = 0; j < 8; ++j)
        rA1[j] = __builtin_nontemporal_load(wp + (size_t)tn * 2048 + j * 32);
      B1 = *reinterpret_cast<const f16x8*>(xp + (size_t)tn * 2048);
      *reinterpret_cast<f16x8*>(wtp + (size_t)(t + 1) * 2048) = a;
      accB = __builtin_amdgcn_mfma_f32_32x32x16_f16(a, b, accB, 0, 0, 0);
    }
  }
#pragma unroll
  for (int r = 0; r < 16; ++r) accA[r] += accB[r];

#pragma unroll
  for (int r = 0; r < 16; ++r)
    red[w][(r & 3) + 8 * (r >> 2) + 4 * h][m] = accA[r];
  __syncthreads();

  float* Pp = P + ((size_t)c * CHUNKS + chunk) * PS;
#pragma unroll
  for (int e = tid; e < 1024; e += 256) {
    const int d = e >> 5, bb = e & 31;
    Pp[e] = red[0][d][bb] + red[1][d][bb] + red[2][d][bb] + red[3][d][bb];
  }
}

// MODE-1 sweep over Wt f16 fragments; CV comes from LDS (sCV[b][d]).
__device__ __forceinline__ void mega_sweep_wt(
    const _Float16* __restrict__ Wt, const _Float16* __restrict__ xt,
    const float (*sCV)[32], float* __restrict__ P, float (*red)[32][33],
    float (*lred)[32], int c, int chunk, int tid) {
  const int w = tid >> 6, l = tid & 63;
  const int m = l & 31, h = l >> 5;
  const int n0 = chunk * CHUNK_N;
  constexpr int TILES = CHUNK_N / 4;

  const _Float16* wp = Wt + ((size_t)c * kN + n0 + w) * 512 + (size_t)l * 8;
  const _Float16* xp = xt + ((size_t)(n0 + w)) * 512 + m * 16 + h * 8;

  float cvr[16];
#pragma unroll
  for (int r = 0; r < 16; ++r)
    cvr[r] = sCV[m][(r & 3) + 8 * (r >> 2) + 4 * h];

  f32x16 accA = zero16(), accB = zero16();
  float lacc = 0.f;
  const f32x16 z = zero16();

  f16x8 A0, A1, B0, B1;
  A0 = *reinterpret_cast<const f16x8*>(wp);
  B0 = *reinterpret_cast<const f16x8*>(xp);
  A1 = *reinterpret_cast<const f16x8*>(wp + 2048);
  B1 = *reinterpret_cast<const f16x8*>(xp + 2048);

#pragma unroll 1
  for (int t = 0; t < TILES; t += 2) {
    {
      const f16x8 a = A0;
      const f16x8 b = B0;
      const int tn = (t + 2 < TILES) ? t + 2 : 0;
      A0 = *reinterpret_cast<const f16x8*>(wp + (size_t)tn * 2048);
      B0 = *reinterpret_cast<const f16x8*>(xp + (size_t)tn * 2048);
      const f32x16 pr =
          __builtin_amdgcn_mfma_f32_32x32x16_f16(a, b, z, 0, 0, 0);
      float d0 = pr[0] * cvr[0], d1 = pr[1] * cvr[1];
      float d2 = pr[2] * cvr[2], d3 = pr[3] * cvr[3];
#pragma unroll
      for (int r = 4; r < 16; r += 4) {
        d0 = fmaf(pr[r + 0], cvr[r + 0], d0);
        d1 = fmaf(pr[r + 1], cvr[r + 1], d1);
        d2 = fmaf(pr[r + 2], cvr[r + 2], d2);
        d3 = fmaf(pr[r + 3], cvr[r + 3], d3);
      }
      float dp = (d0 + d1) + (d2 + d3);
      dp += __shfl_xor(dp, 32);
      const float e = __expf(dp);
      lacc += e;
#pragma unroll
      for (int r = 0; r < 16; ++r) accA[r] = fmaf(e, pr[r], accA[r]);
    }
    {
      const f16x8 a = A1;
      const f16x8 b = B1;
      const int tn = (t + 3 < TILES) ? t + 3 : 0;
      A1 = *reinterpret_cast<const f16x8*>(wp + (size_t)tn * 2048);
      B1 = *reinterpret_cast<const f16x8*>(xp + (size_t)tn * 2048);
      const f32x16 pr =
          __builtin_amdgcn_mfma_f32_32x32x16_f16(a, b, z, 0, 0, 0);
      float d0 = pr[0] * cvr[0], d1 = pr[1] * cvr[1];
      float d2 = pr[2] * cvr[2], d3 = pr[3] * cvr[3];
#pragma unroll
      for (int r = 4; r < 16; r += 4) {
        d0 = fmaf(pr[r + 0], cvr[r + 0], d0);
        d1 = fmaf(pr[r + 1], cvr[r + 1], d1);
        d2 = fmaf(pr[r + 2], cvr[r + 2], d2);
        d3 = fmaf(pr[r + 3], cvr[r + 3], d3);
      }
      float dp = (d0 + d1) + (d2 + d3);
      dp += __shfl_xor(dp, 32);
      const float e = __expf(dp);
      lacc += e;
#pragma unroll
      for (int r = 0; r < 16; ++r) accB[r] = fmaf(e, pr[r], accB[r]);
    }
  }
#pragma unroll
  for (int r = 0; r < 16; ++r) accA[r] += accB[r];

#pragma unroll
  for (int r = 0; r < 16; ++r)
    red[w][(r & 3) + 8 * (r >> 2) + 4 * h][m] = accA[r];
  if (h == 0) lred[w][m] = lacc;
  __syncthreads();

  float* Pp = P + ((size_t)c * CHUNKS + chunk) * PS;
#pragma unroll
  for (int e = tid; e < 1024; e += 256) {
    const int d = e >> 5, bb = e & 31;
    Pp[e] = red[0][d][bb] + red[1][d][bb] + red[2][d][bb] + red[3][d][bb];
  }
  if (tid < 32)
    Pp[1024 + tid] = lred[0][tid] + lred[1][tid] + lred[2][tid] + lred[3][tid];
}

// Redundant per-block reduce over chunks + squash. Agent-scope loads of P
// (cross-XCD producers). t: b = t>>3, dg = t&7 owns d = dg + 8k, k<4.
// K<2: update cvrun and write sCV[b][d]. K==2: write out.
template <int K>
__device__ __forceinline__ void mega_reduce(const float* __restrict__ P,
                                            float* __restrict__ out,
                                            float (&cvrun)[4],
                                            float (*sCV)[32], int c, int t) {
  const int b = t >> 3, dg = t & 7;
  const float* Pc = P + (size_t)c * CHUNKS * PS;
  float s0 = 0.f, s1 = 0.f, s2 = 0.f, s3 = 0.f, lb = 0.f;
#pragma unroll 4
  for (int ch = 0; ch < CHUNKS; ++ch) {
    const float* base = Pc + (size_t)ch * PS;
    s0 += __hip_atomic_load(base + (dg + 0) * 32 + b, __ATOMIC_RELAXED,
                            __HIP_MEMORY_SCOPE_AGENT);
    s1 += __hip_atomic_load(base + (dg + 8) * 32 + b, __ATOMIC_RELAXED,
                            __HIP_MEMORY_SCOPE_AGENT);
    s2 += __hip_atomic_load(base + (dg + 16) * 32 + b, __ATOMIC_RELAXED,
                            __HIP_MEMORY_SCOPE_AGENT);
    s3 += __hip_atomic_load(base + (dg + 24) * 32 + b, __ATOMIC_RELAXED,
                            __HIP_MEMORY_SCOPE_AGENT);
    if (K != 0 && dg == 0)
      lb += __hip_atomic_load(base + 1024 + b, __ATOMIC_RELAXED,
                              __HIP_MEMORY_SCOPE_AGENT);
  }
  float inv;
  if constexpr (K == 0) {
    inv = 1.0f / (float)kN;
  } else {
    lb = __shfl(lb, (t & 63) & 56);  // broadcast from dg==0 lane of b-group
    inv = 1.0f / lb;
  }
  const float v0 = s0 * inv, v1 = s1 * inv, v2 = s2 * inv, v3 = s3 * inv;
  float sn = v0 * v0 + v1 * v1 + v2 * v2 + v3 * v3;
  sn += __shfl_xor(sn, 1);
  sn += __shfl_xor(sn, 2);
  sn += __shfl_xor(sn, 4);  // |s|^2 over all 32 d of this b
  const float coef = sqrtf(sn) / (1.0f + sn);
  if constexpr (K == 2) {
    const size_t o0 = (size_t)c * 1024 + b * 32 + dg;
    out[o0 + 0] = v0 * coef;  out[o0 + 8] = v1 * coef;
    out[o0 + 16] = v2 * coef; out[o0 + 24] = v3 * coef;
  } else {
    if constexpr (K == 0) {
      cvrun[0] = v0 * coef; cvrun[1] = v1 * coef;
      cvrun[2] = v2 * coef; cvrun[3] = v3 * coef;
    } else {
      cvrun[0] += v0 * coef; cvrun[1] += v1 * coef;
      cvrun[2] += v2 * coef; cvrun[3] += v3 * coef;
    }
    sCV[b][dg + 0] = cvrun[0];  sCV[b][dg + 8] = cvrun[1];
    sCV[b][dg + 16] = cvrun[2]; sCV[b][dg + 24] = cvrun[3];
  }
}

__global__ __launch_bounds__(256, 4) void k_mega2(
    const float* __restrict__ W, const _Float16* __restrict__ xt,
    _Float16* __restrict__ Wt, float* __restrict__ P0, float* __restrict__ P1,
    float* __restrict__ P2, unsigned* __restrict__ bar,
    float* __restrict__ out) {
  __shared__ float red[4][32][33];
  __shared__ float lred[4][32];
  __shared__ float sCV[32][32];
  const int bid = blockIdx.x;
  const int c = bid & 31;
  const int chunk = bid >> 5;
  const int tid = threadIdx.x;
  float cvrun[4] = {0.f, 0.f, 0.f, 0.f};

  // Phase A: sweep0 (reads W nt, emits Wt, writes P0)
  mega_sweep0(W, xt, Wt, P0, red, c, chunk, tid);
  bar_arrive(bar, bid, tid);
  bar_wait(bar, tid, 1);

  // Phase B: redundant reduce of P0 -> cvrun, sCV (no barrier needed after:
  // next phase writes P1 != P0 and reads only own-block Wt/xt/sCV)
  mega_reduce<0>(P0, nullptr, cvrun, sCV, c, tid);
  __syncthreads();

  // Phase C: sweep1 over Wt, writes P1
  mega_sweep_wt(Wt, xt, sCV, P1, red, lred, c, chunk, tid);
  bar_arrive(bar, bid, tid);
  bar_wait(bar, tid, 2);

  // Phase D: redundant reduce of P1
  mega_reduce<1>(P1, nullptr, cvrun, sCV, c, tid);
  __syncthreads();

  // Phase E: sweep2 over Wt, writes P2
  mega_sweep_wt(Wt, xt, sCV, P2, red, lred, c, chunk, tid);
  bar_arrive(bar, bid, tid);

  // Phase F: only chunk-0 blocks finish (one per c)
  if (chunk == 0) {
    bar_wait(bar, tid, 3);
    mega_reduce<2>(P2, out, cvrun, sCV, c, tid);
  }
}

// ================= v9 fallback kernels (proven 201us) ======================

template <int MODE, bool EMIT>
__global__ __launch_bounds__(256) void k_sweep(const float* __restrict__ W,
                                               const _Float16* __restrict__ xt,
                                               const float* __restrict__ cumVec,
                                               float* __restrict__ partials,
                                               _Float16* __restrict__ Wt) {
  __shared__ float red[4][32][33];
  __shared__ float lred[4][32];
  const int bid = blockIdx.x;
  const int c = bid & 31;
  const int chunk = bid >> 5;
  const int tid = threadIdx.x;
  const int w = tid >> 6, l = tid & 63;
  const int m = l & 31, h = l >> 5;
  const int n0 = chunk * CHUNK_N;
  constexpr int TILES = CHUNK_N / 4;

  const float* wp = W + ((size_t)c * kN + n0 + w) * 512 + (h * 8) * 32 + m;
  const _Float16* xp = xt + ((size_t)(n0 + w)) * 512 + m * 16 + h * 8;
  _Float16* wtp =
      EMIT ? (Wt + ((size_t)c * kN + n0 + w) * 512 + (size_t)l * 8) : nullptr;

  float cvr[16];
  if (MODE) {
    const float* cvp = cumVec + (size_t)c * 1024 + m * 32;
#pragma unroll
    for (int r = 0; r < 16; ++r) cvr[r] = cvp[(r & 3) + 8 * (r >> 2) + 4 * h];
  }

  f32x16 accA = zero16(), accB = zero16();
  float lacc = 0.f;
  const f32x16 z = zero16();

  float rA0[8], rA1[8];
  f16x8 B0, B1;
#pragma unroll
  for (int j = 0; j < 8; ++j)
    rA0[j] = EMIT ? __builtin_nontemporal_load(wp + j * 32) : wp[j * 32];
  B0 = *reinterpret_cast<const f16x8*>(xp);
#pragma unroll
  for (int j = 0; j < 8; ++j)
    rA1[j] = EMIT ? __builtin_nontemporal_load(wp + 2048 + j * 32)
                  : wp[2048 + j * 32];
  B1 = *reinterpret_cast<const f16x8*>(xp + 2048);

#pragma unroll 1
  for (int t = 0; t < TILES; t += 2) {
    {
      f16x8 a;
#pragma unroll
      for (int j = 0; j < 8; ++j) a[j] = (_Float16)rA0[j];
      const f16x8 b = B0;
      const int tn = (t + 2 < TILES) ? t + 2 : 0;
#pragma unroll
      for (int j = 0; j < 8; ++j)
        rA0[j] = EMIT ? __builtin_nontemporal_load(wp + (size_t)tn * 2048 +
                                                   j * 32)
                      : wp[(size_t)tn * 2048 + j * 32];
      B0 = *reinterpret_cast<const f16x8*>(xp + (size_t)tn * 2048);
      if constexpr (EMIT)
        *reinterpret_cast<f16x8*>(wtp + (size_t)t * 2048) = a;
      if constexpr (MODE == 0) {
        accA = __builtin_amdgcn_mfma_f32_32x32x16_f16(a, b, accA, 0, 0, 0);
      } else {
        const f32x16 pr =
            __builtin_amdgcn_mfma_f32_32x32x16_f16(a, b, z, 0, 0, 0);
        float d0 = pr[0] * cvr[0], d1 = pr[1] * cvr[1];
        float d2 = pr[2] * cvr[2], d3 = pr[3] * cvr[3];
#pragma unroll
        for (int r = 4; r < 16; r += 4) {
          d0 = fmaf(pr[r + 0], cvr[r + 0], d0);
          d1 = fmaf(pr[r + 1], cvr[r + 1], d1);
          d2 = fmaf(pr[r + 2], cvr[r + 2], d2);
          d3 = fmaf(pr[r + 3], cvr[r + 3], d3);
        }
        float dp = (d0 + d1) + (d2 + d3);
        dp += __shfl_xor(dp, 32);
        const float e = __expf(dp);
        lacc += e;
#pragma unroll
        for (int r = 0; r < 16; ++r) accA[r] = fmaf(e, pr[r], accA[r]);
      }
    }
    {
      f16x8 a;
#pragma unroll
      for (int j = 0; j < 8; ++j) a[j] = (_Float16)rA1[j];
      const f16x8 b = B1;
      const int tn = (t + 3 < TILES) ? t + 3 : 0;
#pragma unroll
      for (int j = 0; j < 8; ++j)
        rA1[j] = EMIT ? __builtin_nontemporal_load(wp + (size_t)tn * 2048 +
                                                   j * 32)
                      : wp[(size_t)tn * 2048 + j * 32];
      B1 = *reinterpret_cast<const f16x8*>(xp + (size_t)tn * 2048);
      if constexpr (EMIT)
        *reinterpret_cast<f16x8*>(wtp + (size_t)(t + 1) * 2048) = a;
      if constexpr (MODE == 0) {
        accB = __builtin_amdgcn_mfma_f32_32x32x16_f16(a, b, accB, 0, 0, 0);
      } else {
        const f32x16 pr =
            __builtin_amdgcn_mfma_f32_32x32x16_f16(a, b, z, 0, 0, 0);
        float d0 = pr[0] * cvr[0], d1 = pr[1] * cvr[1];
        float d2 = pr[2] * cvr[2], d3 = pr[3] * cvr[3];
#pragma unroll
        for (int r = 4; r < 16; r += 4) {
          d0 = fmaf(pr[r + 0], cvr[r + 0], d0);
          d1 = fmaf(pr[r + 1], cvr[r + 1], d1);
          d2 = fmaf(pr[r + 2], cvr[r + 2], d2);
          d3 = fmaf(pr[r + 3], cvr[r + 3], d3);
        }
        float dp = (d0 + d1) + (d2 + d3);
        dp += __shfl_xor(dp, 32);
        const float e = __expf(dp);
        lacc += e;
#pragma unroll
        for (int r = 0; r < 16; ++r) accB[r] = fmaf(e, pr[r], accB[r]);
      }
    }
  }
#pragma unroll
  for (int r = 0; r < 16; ++r) accA[r] += accB[r];

#pragma unroll
  for (int r = 0; r < 16; ++r)
    red[w][(r & 3) + 8 * (r >> 2) + 4 * h][m] = accA[r];
  if (MODE && h == 0) lred[w][m] = lacc;
  __syncthreads();

  float* Pp = partials + ((size_t)c * CHUNKS + chunk) * PS;
#pragma unroll
  for (int e = tid; e < 1024; e += 256) {
    const int d = e >> 5, bb = e & 31;
    Pp[e] = red[0][d][bb] + red[1][d][bb] + red[2][d][bb] + red[3][d][bb];
  }
  if (MODE && tid < 32)
    Pp[1024 + tid] = lred[0][tid] + lred[1][tid] + lred[2][tid] + lred[3][tid];
}

__global__ __launch_bounds__(256) void k_sweep_wt(
    const _Float16* __restrict__ Wt, const _Float16* __restrict__ xt,
    const float* __restrict__ cumVec, float* __restrict__ partials) {
  __shared__ float red[4][32][33];
  __shared__ float lred[4][32];
  __shared__ float sCV[32][32];
  const int bid = blockIdx.x;
  const int c = bid & 31;
  const int chunk = bid >> 5;
  const int tid = threadIdx.x;
  // load global CV into sCV, then reuse the shared-CV sweep body
  for (int e = tid; e < 1024; e += 256)
    sCV[e >> 5][e & 31] = cumVec[(size_t)c * 1024 + e];
  __syncthreads();
  mega_sweep_wt(Wt, xt, sCV, partials, red, lred, c, chunk, tid);
}

template <int K>
__global__ __launch_bounds__(1024) void k_reduce(
    const float* __restrict__ partials, float* __restrict__ CV,
    float* __restrict__ out) {
  const int c = blockIdx.x;
  const int t = threadIdx.x;
  const int b = t >> 5, d = t & 31;
  const float* Pc = partials + (size_t)c * CHUNKS * PS;
  float s = 0.f;
#pragma unroll 4
  for (int ch = 0; ch < CHUNKS; ++ch) s += Pc[(size_t)ch * PS + d * 32 + b];
  float inv;
  if constexpr (K == 0) {
    inv = 1.0f / (float)kN;
  } else {
    float lb = 0.f;
#pragma unroll 4
    for (int ch = 0; ch < CHUNKS; ++ch) lb += Pc[(size_t)ch * PS + 1024 + b];
    inv = 1.0f / lb;
  }
  const float sv = s * inv;
  float sn = sv * sv;
  sn += __shfl_xor(sn, 1);
  sn += __shfl_xor(sn, 2);
  sn += __shfl_xor(sn, 4);
  sn += __shfl_xor(sn, 8);
  sn += __shfl_xor(sn, 16);
  const float coef = sqrtf(sn) / (1.0f + sn);
  const float o = sv * coef;
  if constexpr (K == 2)
    out[(size_t)c * 1024 + t] = o;
  else if constexpr (K == 0)
    CV[(size_t)c * 1024 + t] = o;
  else
    CV[(size_t)c * 1024 + t] += o;
}

// ---------------- v1 single-kernel fallback (no ws; passed @~590us) --------
namespace v1 {
constexpr int BG = 4, NSLOT = 128, THREADS1 = NSLOT * 8;
template <int MODE>
__device__ __forceinline__ void sweep_pass(const float* __restrict__ Wc,
                                           const float* __restrict__ x, int b0,
                                           int tid, int nslot, int dg,
                                           float (*red)[8][20], float (*sS)[kD],
                                           float* sL, const float (*sVec)[kD]) {
  float acc[BG][4];
  float lv[BG];
#pragma unroll
  for (int b = 0; b < BG; ++b) {
    lv[b] = 0.f;
#pragma unroll
    for (int j = 0; j < 4; ++j) acc[b][j] = 0.f;
  }
  float vec[BG][4];
  if (MODE) {
#pragma unroll
    for (int b = 0; b < BG; ++b)
#pragma unroll
      for (int j = 0; j < 4; ++j) vec[b][j] = sVec[b][4 * dg + j];
  }
#pragma unroll 1
  for (int n = nslot; n < kN; n += NSLOT) {
    const float* Wn = Wc + (size_t)n * (kI * kD) + 4 * dg;
    float pr[BG][4];
#pragma unroll
    for (int b = 0; b < BG; ++b)
#pragma unroll
      for (int j = 0; j < 4; ++j) pr[b][j] = 0.f;
#pragma unroll
    for (int iq = 0; iq < 4; ++iq) {
      float4 wv[4];
#pragma unroll
      for (int r = 0; r < 4; ++r)
        wv[r] = *reinterpret_cast<const float4*>(Wn + (4 * iq + r) * kD);
#pragma unroll
      for (int b = 0; b < BG; ++b) {
        const float4 xv = *reinterpret_cast<const float4*>(
            x + ((size_t)(b0 + b) * kN + n) * kI + 4 * iq);
        const float xsv[4] = {xv.x, xv.y, xv.z, xv.w};
#pragma unroll
        for (int r = 0; r < 4; ++r) {
          pr[b][0] = fmaf(xsv[r], wv[r].x, pr[b][0]);
          pr[b][1] = fmaf(xsv[r], wv[r].y, pr[b][1]);
          pr[b][2] = fmaf(xsv[r], wv[r].z, pr[b][2]);
          pr[b][3] = fmaf(xsv[r], wv[r].w, pr[b][3]);
        }
      }
    }
    if (MODE == 0) {
#pragma unroll
      for (int b = 0; b < BG; ++b)
#pragma unroll
        for (int j = 0; j < 4; ++j) acc[b][j] += pr[b][j];
    } else {
#pragma unroll
      for (int b = 0; b < BG; ++b) {
        float dp = pr[b][0] * vec[b][0] + pr[b][1] * vec[b][1] +
                   pr[b][2] * vec[b][2] + pr[b][3] * vec[b][3];
        dp += __shfl_xor(dp, 1);
        dp += __shfl_xor(dp, 2);
        dp += __shfl_xor(dp, 4);
        const float e = __expf(dp);
        lv[b] += e;
        acc[b][0] = fmaf(e, pr[b][0], acc[b][0]);
        acc[b][1] = fmaf(e, pr[b][1], acc[b][1]);
        acc[b][2] = fmaf(e, pr[b][2], acc[b][2]);
        acc[b][3] = fmaf(e, pr[b][3], acc[b][3]);
      }
    }
  }
#pragma unroll
  for (int b = 0; b < BG; ++b) {
#pragma unroll
    for (int j = 0; j < 4; ++j) {
      float v = acc[b][j];
      v += __shfl_xor(v, 8);
      v += __shfl_xor(v, 16);
      v += __shfl_xor(v, 32);
      acc[b][j] = v;
    }
    if (MODE) {
      float v = lv[b];
      v += __shfl_xor(v, 8);
      v += __shfl_xor(v, 16);
      v += __shfl_xor(v, 32);
      lv[b] = v;
    }
  }
  const int lane = tid & 63;
  const int wv_id = tid >> 6;
  if ((lane >> 3) == 0) {
#pragma unroll
    for (int b = 0; b < BG; ++b) {
#pragma unroll
      for (int j = 0; j < 4; ++j) red[wv_id][dg][4 * b + j] = acc[b][j];
      if (MODE) red[wv_id][dg][16 + b] = lv[b];
    }
  }
  __syncthreads();
  if (tid < 128) {
    const int dgc = tid >> 4, e = tid & 15;
    float s = 0.f;
#pragma unroll
    for (int w = 0; w < 16; ++w) s += red[w][dgc][e];
    sS[e >> 2][4 * dgc + (e & 3)] = s;
  }
  if (MODE && tid >= 128 && tid < 128 + BG) {
    const int b = tid - 128;
    float s = 0.f;
#pragma unroll
    for (int w = 0; w < 16; ++w) s += red[w][0][16 + b];
    sL[b] = s;
  }
  __syncthreads();
}

__global__ __launch_bounds__(THREADS1, 4) void caps_route_kernel(
    const float* __restrict__ x, const float* __restrict__ W,
    float* __restrict__ out) {
  __shared__ float red[16][8][20];
  __shared__ float sS[BG][kD];
  __shared__ float sVec[BG][kD];
  __shared__ float sL[BG];
  const int i = blockIdx.x;
  const int xcd = i & 7;
  const int j = i >> 3;
  const int c = xcd + 8 * (j >> 3);
  const int b0 = 4 * (j & 7);
  const int tid = threadIdx.x;
  const int nslot = tid >> 3;
  const int dg = tid & 7;
  const float* Wc = W + (size_t)c * kN * kI * kD;
  sweep_pass<0>(Wc, x, b0, tid, nslot, dg, red, sS, sL, sVec);
  if (tid < BG) {
    const int b = tid;
    float sval[kD], sn = 0.f;
    const float inv = 1.0f / (float)kN;
#pragma unroll
    for (int d = 0; d < kD; ++d) {
      sval[d] = sS[b][d] * inv;
      sn += sval[d] * sval[d];
    }
    const float coef = sqrtf(sn) / (1.0f + sn);
#pragma unroll
    for (int d = 0; d < kD; ++d) sVec[b][d] = sval[d] * coef;
  }
  __syncthreads();
  sweep_pass<1>(Wc, x, b0, tid, nslot, dg, red, sS, sL, sVec);
  if (tid < BG) {
    const int b = tid;
    float sval[kD], sn = 0.f;
    const float inv = 1.0f / sL[b];
#pragma unroll
    for (int d = 0; d < kD; ++d) {
      sval[d] = sS[b][d] * inv;
      sn += sval[d] * sval[d];
    }
    const float coef = sqrtf(sn) / (1.0f + sn);
#pragma unroll
    for (int d = 0; d < kD; ++d) sVec[b][d] += sval[d] * coef;
  }
  __syncthreads();
  sweep_pass<1>(Wc, x, b0, tid, nslot, dg, red, sS, sL, sVec);
  if (tid < BG) {
    const int b = tid;
    float sval[kD], sn = 0.f;
    const float inv = 1.0f / sL[b];
#pragma unroll
    for (int d = 0; d < kD; ++d) {
      sval[d] = sS[b][d] * inv;
      sn += sval[d] * sval[d];
    }
    const float coef = sqrtf(sn) / (1.0f + sn);
    float* o = out + ((size_t)c * kB + (b0 + b)) * kD;
#pragma unroll
    for (int d = 0; d < kD; ++d) o[d] = sval[d] * coef;
  }
}
}  // namespace v1

extern "C" void kernel_launch(void* const* d_in, const int* in_sizes, int n_in,
                              void* d_out, int out_size, void* d_ws,
                              size_t ws_size, hipStream_t stream) {
  const float* x = (const float*)d_in[0];  // [B,N,IN] fp32
  const float* W = (const float*)d_in[1];  // [C,N,IN,OUT] fp32
  float* out = (float*)d_out;              // [C,B,1,1,OUT] fp32
  (void)in_sizes; (void)n_in; (void)out_size;

  // One-time co-residency check for the software grid barrier (host-only
  // queries; legal during graph capture). Requires 4 blocks/CU x 256 CUs.
  static int s_mega = -1;
  if (s_mega < 0) {
    int dev = 0;
    (void)hipGetDevice(&dev);
    int nCU = 0;
    (void)hipDeviceGetAttribute(&nCU, hipDeviceAttributeMultiprocessorCount,
                                dev);
    int maxB = 0;
    (void)hipOccupancyMaxActiveBlocksPerMultiprocessor(&maxB, k_mega2, 256, 0);
    s_mega = (nCU > 0 && maxB > 0 && (size_t)nCU * (size_t)maxB >= (size_t)GRID)
                 ? 1
                 : 0;
  }

  if (s_mega == 1 && ws_size >= WS_BYTES_MEGA) {
    _Float16* xt = (_Float16*)d_ws;
    _Float16* Wt = xt + XT_ELEMS;
    float* P0 = (float*)(Wt + WT_ELEMS);
    float* P1 = P0 + P_FLOATS;
    float* P2 = P1 + P_FLOATS;
    unsigned* bar = (unsigned*)(P2 + P_FLOATS);  // 16B-aligned; zeroed by k_xt

    k_xt<<<GRID, 256, 0, stream>>>(x, xt, bar);
    k_mega2<<<GRID, 256, 0, stream>>>(W, xt, Wt, P0, P1, P2, bar, out);
    return;
  }

  if (ws_size >= WS_BYTES_BIG) {
    _Float16* xt = (_Float16*)d_ws;
    _Float16* Wt = xt + XT_ELEMS;
    float* P = (float*)(Wt + WT_ELEMS);
    float* CV = P + P_FLOATS;

    k_xt<<<GRID, 256, 0, stream>>>(x, xt, nullptr);
    k_sweep<0, true><<<GRID, 256, 0, stream>>>(W, xt, nullptr, P, Wt);
    k_reduce<0><<<kC, 1024, 0, stream>>>(P, CV, nullptr);
    k_sweep_wt<<<GRID, 256, 0, stream>>>(Wt, xt, CV, P);
    k_reduce<1><<<kC, 1024, 0, stream>>>(P, CV, nullptr);
    k_sweep_wt<<<GRID, 256, 0, stream>>>(Wt, xt, CV, P);
    k_reduce<2><<<kC, 1024, 0, stream>>>(P, nullptr, out);
    return;
  }

  if (ws_size >= WS_BYTES_MID) {
    _Float16* xt = (_Float16*)d_ws;
    float* P = (float*)(xt + XT_ELEMS);
    float* CV = P + P_FLOATS;

    k_xt<<<GRID, 256, 0, stream>>>(x, xt, nullptr);
    k_sweep<0, false><<<GRID, 256, 0, stream>>>(W, xt, nullptr, P, nullptr);
    k_reduce<0><<<kC, 1024, 0, stream>>>(P, CV, nullptr);
    k_sweep<1, false><<<GRID, 256, 0, stream>>>(W, xt, CV, P, nullptr);
    k_reduce<1><<<kC, 1024, 0, stream>>>(P, CV, nullptr);
    k_sweep<1, false><<<GRID, 256, 0, stream>>>(W, xt, CV, P, nullptr);
    k_reduce<2><<<kC, 1024, 0, stream>>>(P, nullptr, out);
    return;
  }

  v1::caps_route_kernel<<<256, v1::THREADS1, 0, stream>>>(x, W, out);
}

// Round 4
// 200.685 us; speedup vs baseline: 1.0121x; 1.0000x over previous
//
#include <hip/hip_runtime.h>
#include <math.h>

// CapsuleLayer dynamic routing. C=32,B=32,N=4096,IN=16,OUT=32, 3 iters.
// v12: v11 fused persistent kernel, with the two measured failures fixed.
// v11 diagnosis (rocprof): timed path fell back to v9 (200.69us == v9) because
// the occupancy probe runs under graph capture and errors -> gate=0. And
// k_mega2 ran 968us with VALUBusy 2.8% / FETCH at the byte model: the
// per-iteration AGENT-scope ACQUIRE spin load invalidates L2 every poll,
// thrashing the XCD's cache for all co-resident blocks.
// Fixes: (1) probe co-residency in a global ctor at dlopen (never under
// capture) + lazy retry; (2) barrier = release arrivals, RELAXED spin +
// s_sleep, single ACQUIRE load after the spin exits.
// Everything else identical to v11 (numerics proven by pytest pass).

typedef _Float16 f16x8 __attribute__((ext_vector_type(8)));
typedef float f32x16 __attribute__((ext_vector_type(16)));

namespace {
constexpr int kC = 32, kB = 32, kN = 4096, kI = 16, kD = 32;
constexpr int CHUNKS = 32;            // n-chunks per c
constexpr int CHUNK_N = kN / CHUNKS;  // 128
constexpr int PS = kB * kD + kB;      // 1056 floats per (c,chunk) partial
constexpr int GRID = kC * CHUNKS;     // 1024 blocks
constexpr size_t XT_ELEMS = (size_t)kN * kB * kI;       // f16 [n][b][i]
constexpr size_t WT_ELEMS = (size_t)kC * kN * kI * kD;  // f16 fragment layout
constexpr size_t P_FLOATS = (size_t)kC * CHUNKS * PS;
constexpr size_t CV_FLOATS = (size_t)kC * kB * kD;
constexpr int BAR_U32 = 33;  // [0..31] per-c group counters, [32] root
constexpr size_t WS_BYTES_MID = XT_ELEMS * 2 + (P_FLOATS + CV_FLOATS) * 4;
constexpr size_t WS_BYTES_BIG =
    (XT_ELEMS + WT_ELEMS) * 2 + (P_FLOATS + CV_FLOATS) * 4;
constexpr size_t WS_BYTES_MEGA =
    (XT_ELEMS + WT_ELEMS) * 2 + 3 * P_FLOATS * 4 + 256;
}  // namespace

__device__ __forceinline__ f32x16 zero16() {
  f32x16 z;
#pragma unroll
  for (int r = 0; r < 16; ++r) z[r] = 0.f;
  return z;
}

// ---- k_xt: x[b][n][i] f32 -> xt[n][b][i] f16; also zeroes barrier ctrs ----
__global__ __launch_bounds__(256) void k_xt(const float* __restrict__ x,
                                            _Float16* __restrict__ xt,
                                            unsigned* __restrict__ bar) {
  if (bar && blockIdx.x == 0 && threadIdx.x < BAR_U32) bar[threadIdx.x] = 0u;
  const int t = blockIdx.x * 256 + threadIdx.x;  // [0, 262144) == 2*B*N
  const int r = t >> 1, half = t & 1;            // r = b*4096 + n
  const int b = r >> 12, n = r & 4095;
  const float4* s4 =
      reinterpret_cast<const float4*>(x) + (size_t)r * 4 + half * 2;
  const float4 f0 = s4[0], f1 = s4[1];
  f16x8 o;
  o[0] = (_Float16)f0.x; o[1] = (_Float16)f0.y;
  o[2] = (_Float16)f0.z; o[3] = (_Float16)f0.w;
  o[4] = (_Float16)f1.x; o[5] = (_Float16)f1.y;
  o[6] = (_Float16)f1.z; o[7] = (_Float16)f1.w;
  *reinterpret_cast<f16x8*>(xt + ((size_t)n * kB + b) * kI + half * 8) = o;
}

// ---- custom grid barrier: 2-level, epoch-based ----------------------------
// arrive: threadfence (wbL2) then RELEASE adds; last of 32 same-c blocks
// bumps root. wait: RELAXED spin (no cache side effects) + one ACQUIRE load.
__device__ __forceinline__ void bar_arrive(unsigned* bar, int bid, int tid) {
  __threadfence();   // publish this block's plain stores to agent scope
  __syncthreads();   // all threads of block fenced
  if (tid == 0) {
    const int g = bid & 31;
    unsigned v = __hip_atomic_fetch_add(&bar[g], 1u, __ATOMIC_RELEASE,
                                        __HIP_MEMORY_SCOPE_AGENT);
    if ((v & 31u) == 31u)
      __hip_atomic_fetch_add(&bar[32], 1u, __ATOMIC_RELEASE,
                             __HIP_MEMORY_SCOPE_AGENT);
  }
}

__device__ __forceinline__ void bar_wait(unsigned* bar, int tid, int epoch) {
  if (tid == 0) {
    const unsigned target = 32u * (unsigned)epoch;
    // Relaxed polling: agent-scope relaxed load has no invalidate side
    // effect (v11's per-iteration ACQUIRE invalidated L2 -> 968us).
    while (__hip_atomic_load(&bar[32], __ATOMIC_RELAXED,
                             __HIP_MEMORY_SCOPE_AGENT) < target)
      __builtin_amdgcn_s_sleep(8);
    // Single acquire to order subsequent reads after observed arrivals.
    (void)__hip_atomic_load(&bar[32], __ATOMIC_ACQUIRE,
                            __HIP_MEMORY_SCOPE_AGENT);
  }
  __syncthreads();
}

// ================= fused-kernel phase bodies ===============================

// Sweep 0: MODE 0 (uniform probs, acc in MFMA C) + EMIT Wt f16 fragments.
__device__ __forceinline__ void mega_sweep0(const float* __restrict__ W,
                                            const _Float16* __restrict__ xt,
                                            _Float16* __restrict__ Wt,
                                            float* __restrict__ P,
                                            float (*red)[32][33], int c,
                                            int chunk, int tid) {
  const int w = tid >> 6, l = tid & 63;
  const int m = l & 31, h = l >> 5;
  const int n0 = chunk * CHUNK_N;
  constexpr int TILES = CHUNK_N / 4;

  const float* wp = W + ((size_t)c * kN + n0 + w) * 512 + (h * 8) * 32 + m;
  const _Float16* xp = xt + ((size_t)(n0 + w)) * 512 + m * 16 + h * 8;
  _Float16* wtp = Wt + ((size_t)c * kN + n0 + w) * 512 + (size_t)l * 8;

  f32x16 accA = zero16(), accB = zero16();

  float rA0[8], rA1[8];
  f16x8 B0, B1;
#pragma unroll
  for (int j = 0; j < 8; ++j) rA0[j] = __builtin_nontemporal_load(wp + j * 32);
  B0 = *reinterpret_cast<const f16x8*>(xp);
#pragma unroll
  for (int j = 0; j < 8; ++j)
    rA1[j] = __builtin_nontemporal_load(wp + 2048 + j * 32);
  B1 = *reinterpret_cast<const f16x8*>(xp + 2048);

#pragma unroll 1
  for (int t = 0; t < TILES; t += 2) {
    {
      f16x8 a;
#pragma unroll
      for (int j = 0; j < 8; ++j) a[j] = (_Float16)rA0[j];
      const f16x8 b = B0;
      const int tn = (t + 2 < TILES) ? t + 2 : 0;
#pragma unroll
      for (int j = 0; j < 8; ++j)
        rA0[j] = __builtin_nontemporal_load(wp + (size_t)tn * 2048 + j * 32);
      B0 = *reinterpret_cast<const f16x8*>(xp + (size_t)tn * 2048);
      *reinterpret_cast<f16x8*>(wtp + (size_t)t * 2048) = a;
      accA = __builtin_amdgcn_mfma_f32_32x32x16_f16(a, b, accA, 0, 0, 0);
    }
    {
      f16x8 a;
#pragma unroll
      for (int j = 0; j < 8; ++j) a[j] = (_Float16)rA1[j];
      const f16x8 b = B1;
      const int tn = (t + 3 < TILES) ? t + 3 : 0;
#pragma unroll
      for (int j = 0; j < 8; ++j)
        rA1[j] = __builtin_nontemporal_load(wp + (size_t)tn * 2048 + j * 32);
      B1 = *reinterpret_cast<const f16x8*>(xp + (size_t)tn * 2048);
      *reinterpret_cast<f16x8*>(wtp + (size_t)(t + 1) * 2048) = a;
      accB = __builtin_amdgcn_mfma_f32_32x32x16_f16(a, b, accB, 0, 0, 0);
    }
  }
#pragma unroll
  for (int r = 0; r < 16; ++r) accA[r] += accB[r];

#pragma unroll
  for (int r = 0; r < 16; ++r)
    red[w][(r & 3) + 8 * (r >> 2) + 4 * h][m] = accA[r];
  __syncthreads();

  float* Pp = P + ((size_t)c * CHUNKS + chunk) * PS;
#pragma unroll
  for (int e = tid; e < 1024; e += 256) {
    const int d = e >> 5, bb = e & 31;
    Pp[e] = red[0][d][bb] + red[1][d][bb] + red[2][d][bb] + red[3][d][bb];
  }
}

// MODE-1 sweep over Wt f16 fragments; CV comes from LDS (sCV[b][d]).
__device__ __forceinline__ void mega_sweep_wt(
    const _Float16* __restrict__ Wt, const _Float16* __restrict__ xt,
    const float (*sCV)[32], float* __restrict__ P, float (*red)[32][33],
    float (*lred)[32], int c, int chunk, int tid) {
  const int w = tid >> 6, l = tid & 63;
  const int m = l & 31, h = l >> 5;
  const int n0 = chunk * CHUNK_N;
  constexpr int TILES = CHUNK_N / 4;

  const _Float16* wp = Wt + ((size_t)c * kN + n0 + w) * 512 + (size_t)l * 8;
  const _Float16* xp = xt + ((size_t)(n0 + w)) * 512 + m * 16 + h * 8;

  float cvr[16];
#pragma unroll
  for (int r = 0; r < 16; ++r)
    cvr[r] = sCV[m][(r & 3) + 8 * (r >> 2) + 4 * h];

  f32x16 accA = zero16(), accB = zero16();
  float lacc = 0.f;
  const f32x16 z = zero16();

  f16x8 A0, A1, B0, B1;
  A0 = *reinterpret_cast<const f16x8*>(wp);
  B0 = *reinterpret_cast<const f16x8*>(xp);
  A1 = *reinterpret_cast<const f16x8*>(wp + 2048);
  B1 = *reinterpret_cast<const f16x8*>(xp + 2048);

#pragma unroll 1
  for (int t = 0; t < TILES; t += 2) {
    {
      const f16x8 a = A0;
      const f16x8 b = B0;
      const int tn = (t + 2 < TILES) ? t + 2 : 0;
      A0 = *reinterpret_cast<const f16x8*>(wp + (size_t)tn * 2048);
      B0 = *reinterpret_cast<const f16x8*>(xp + (size_t)tn * 2048);
      const f32x16 pr =
          __builtin_amdgcn_mfma_f32_32x32x16_f16(a, b, z, 0, 0, 0);
      float d0 = pr[0] * cvr[0], d1 = pr[1] * cvr[1];
      float d2 = pr[2] * cvr[2], d3 = pr[3] * cvr[3];
#pragma unroll
      for (int r = 4; r < 16; r += 4) {
        d0 = fmaf(pr[r + 0], cvr[r + 0], d0);
        d1 = fmaf(pr[r + 1], cvr[r + 1], d1);
        d2 = fmaf(pr[r + 2], cvr[r + 2], d2);
        d3 = fmaf(pr[r + 3], cvr[r + 3], d3);
      }
      float dp = (d0 + d1) + (d2 + d3);
      dp += __shfl_xor(dp, 32);
      const float e = __expf(dp);
      lacc += e;
#pragma unroll
      for (int r = 0; r < 16; ++r) accA[r] = fmaf(e, pr[r], accA[r]);
    }
    {
      const f16x8 a = A1;
      const f16x8 b = B1;
      const int tn = (t + 3 < TILES) ? t + 3 : 0;
      A1 = *reinterpret_cast<const f16x8*>(wp + (size_t)tn * 2048);
      B1 = *reinterpret_cast<const f16x8*>(xp + (size_t)tn * 2048);
      const f32x16 pr =
          __builtin_amdgcn_mfma_f32_32x32x16_f16(a, b, z, 0, 0, 0);
      float d0 = pr[0] * cvr[0], d1 = pr[1] * cvr[1];
      float d2 = pr[2] * cvr[2], d3 = pr[3] * cvr[3];
#pragma unroll
      for (int r = 4; r < 16; r += 4) {
        d0 = fmaf(pr[r + 0], cvr[r + 0], d0);
        d1 = fmaf(pr[r + 1], cvr[r + 1], d1);
        d2 = fmaf(pr[r + 2], cvr[r + 2], d2);
        d3 = fmaf(pr[r + 3], cvr[r + 3], d3);
      }
      float dp = (d0 + d1) + (d2 + d3);
      dp += __shfl_xor(dp, 32);
      const float e = __expf(dp);
      lacc += e;
#pragma unroll
      for (int r = 0; r < 16; ++r) accB[r] = fmaf(e, pr[r], accB[r]);
    }
  }
#pragma unroll
  for (int r = 0; r < 16; ++r) accA[r] += accB[r];

#pragma unroll
  for (int r = 0; r < 16; ++r)
    red[w][(r & 3) + 8 * (r >> 2) + 4 * h][m] = accA[r];
  if (h == 0) lred[w][m] = lacc;
  __syncthreads();

  float* Pp = P + ((size_t)c * CHUNKS + chunk) * PS;
#pragma unroll
  for (int e = tid; e < 1024; e += 256) {
    const int d = e >> 5, bb = e & 31;
    Pp[e] = red[0][d][bb] + red[1][d][bb] + red[2][d][bb] + red[3][d][bb];
  }
  if (tid < 32)
    Pp[1024 + tid] = lred[0][tid] + lred[1][tid] + lred[2][tid] + lred[3][tid];
}

// Redundant per-block reduce over chunks + squash. Agent-scope RELAXED loads
// (sc1: bypass local L2, no invalidate) of P written by cross-XCD producers.
template <int K>
__device__ __forceinline__ void mega_reduce(const float* __restrict__ P,
                                            float* __restrict__ out,
                                            float (&cvrun)[4],
                                            float (*sCV)[32], int c, int t) {
  const int b = t >> 3, dg = t & 7;
  const float* Pc = P + (size_t)c * CHUNKS * PS;
  float s0 = 0.f, s1 = 0.f, s2 = 0.f, s3 = 0.f, lb = 0.f;
#pragma unroll 4
  for (int ch = 0; ch < CHUNKS; ++ch) {
    const float* base = Pc + (size_t)ch * PS;
    s0 += __hip_atomic_load(base + (dg + 0) * 32 + b, __ATOMIC_RELAXED,
                            __HIP_MEMORY_SCOPE_AGENT);
    s1 += __hip_atomic_load(base + (dg + 8) * 32 + b, __ATOMIC_RELAXED,
                            __HIP_MEMORY_SCOPE_AGENT);
    s2 += __hip_atomic_load(base + (dg + 16) * 32 + b, __ATOMIC_RELAXED,
                            __HIP_MEMORY_SCOPE_AGENT);
    s3 += __hip_atomic_load(base + (dg + 24) * 32 + b, __ATOMIC_RELAXED,
                            __HIP_MEMORY_SCOPE_AGENT);
    if (K != 0 && dg == 0)
      lb += __hip_atomic_load(base + 1024 + b, __ATOMIC_RELAXED,
                              __HIP_MEMORY_SCOPE_AGENT);
  }
  float inv;
  if constexpr (K == 0) {
    inv = 1.0f / (float)kN;
  } else {
    lb = __shfl(lb, (t & 63) & 56);  // broadcast from dg==0 lane of b-group
    inv = 1.0f / lb;
  }
  const float v0 = s0 * inv, v1 = s1 * inv, v2 = s2 * inv, v3 = s3 * inv;
  float sn = v0 * v0 + v1 * v1 + v2 * v2 + v3 * v3;
  sn += __shfl_xor(sn, 1);
  sn += __shfl_xor(sn, 2);
  sn += __shfl_xor(sn, 4);  // |s|^2 over all 32 d of this b
  const float coef = sqrtf(sn) / (1.0f + sn);
  if constexpr (K == 2) {
    const size_t o0 = (size_t)c * 1024 + b * 32 + dg;
    out[o0 + 0] = v0 * coef;  out[o0 + 8] = v1 * coef;
    out[o0 + 16] = v2 * coef; out[o0 + 24] = v3 * coef;
  } else {
    if constexpr (K == 0) {
      cvrun[0] = v0 * coef; cvrun[1] = v1 * coef;
      cvrun[2] = v2 * coef; cvrun[3] = v3 * coef;
    } else {
      cvrun[0] += v0 * coef; cvrun[1] += v1 * coef;
      cvrun[2] += v2 * coef; cvrun[3] += v3 * coef;
    }
    sCV[b][dg + 0] = cvrun[0];  sCV[b][dg + 8] = cvrun[1];
    sCV[b][dg + 16] = cvrun[2]; sCV[b][dg + 24] = cvrun[3];
  }
}

__global__ __launch_bounds__(256, 4) void k_mega2(
    const float* __restrict__ W, const _Float16* __restrict__ xt,
    _Float16* __restrict__ Wt, float* __restrict__ P0, float* __restrict__ P1,
    float* __restrict__ P2, unsigned* __restrict__ bar,
    float* __restrict__ out) {
  __shared__ float red[4][32][33];
  __shared__ float lred[4][32];
  __shared__ float sCV[32][32];
  const int bid = blockIdx.x;
  const int c = bid & 31;
  const int chunk = bid >> 5;
  const int tid = threadIdx.x;
  float cvrun[4] = {0.f, 0.f, 0.f, 0.f};

  // Phase A: sweep0 (reads W nt, emits Wt, writes P0)
  mega_sweep0(W, xt, Wt, P0, red, c, chunk, tid);
  bar_arrive(bar, bid, tid);
  bar_wait(bar, tid, 1);

  // Phase B: redundant reduce of P0 -> cvrun, sCV
  mega_reduce<0>(P0, nullptr, cvrun, sCV, c, tid);
  __syncthreads();

  // Phase C: sweep1 over Wt, writes P1
  mega_sweep_wt(Wt, xt, sCV, P1, red, lred, c, chunk, tid);
  bar_arrive(bar, bid, tid);
  bar_wait(bar, tid, 2);

  // Phase D: redundant reduce of P1
  mega_reduce<1>(P1, nullptr, cvrun, sCV, c, tid);
  __syncthreads();

  // Phase E: sweep2 over Wt, writes P2
  mega_sweep_wt(Wt, xt, sCV, P2, red, lred, c, chunk, tid);
  bar_arrive(bar, bid, tid);

  // Phase F: only chunk-0 blocks finish (one per c)
  if (chunk == 0) {
    bar_wait(bar, tid, 3);
    mega_reduce<2>(P2, out, cvrun, sCV, c, tid);
  }
}

// ================= v9 fallback kernels (proven 201us) ======================

template <int MODE, bool EMIT>
__global__ __launch_bounds__(256) void k_sweep(const float* __restrict__ W,
                                               const _Float16* __restrict__ xt,
                                               const float* __restrict__ cumVec,
                                               float* __restrict__ partials,
                                               _Float16* __restrict__ Wt) {
  __shared__ float red[4][32][33];
  __shared__ float lred[4][32];
  const int bid = blockIdx.x;
  const int c = bid & 31;
  const int chunk = bid >> 5;
  const int tid = threadIdx.x;
  const int w = tid >> 6, l = tid & 63;
  const int m = l & 31, h = l >> 5;
  const int n0 = chunk * CHUNK_N;
  constexpr int TILES = CHUNK_N / 4;

  const float* wp = W + ((size_t)c * kN + n0 + w) * 512 + (h * 8) * 32 + m;
  const _Float16* xp = xt + ((size_t)(n0 + w)) * 512 + m * 16 + h * 8;
  _Float16* wtp =
      EMIT ? (Wt + ((size_t)c * kN + n0 + w) * 512 + (size_t)l * 8) : nullptr;

  float cvr[16];
  if (MODE) {
    const float* cvp = cumVec + (size_t)c * 1024 + m * 32;
#pragma unroll
    for (int r = 0; r < 16; ++r) cvr[r] = cvp[(r & 3) + 8 * (r >> 2) + 4 * h];
  }

  f32x16 accA = zero16(), accB = zero16();
  float lacc = 0.f;
  const f32x16 z = zero16();

  float rA0[8], rA1[8];
  f16x8 B0, B1;
#pragma unroll
  for (int j = 0; j < 8; ++j)
    rA0[j] = EMIT ? __builtin_nontemporal_load(wp + j * 32) : wp[j * 32];
  B0 = *reinterpret_cast<const f16x8*>(xp);
#pragma unroll
  for (int j = 0; j < 8; ++j)
    rA1[j] = EMIT ? __builtin_nontemporal_load(wp + 2048 + j * 32)
                  : wp[2048 + j * 32];
  B1 = *reinterpret_cast<const f16x8*>(xp + 2048);

#pragma unroll 1
  for (int t = 0; t < TILES; t += 2) {
    {
      f16x8 a;
#pragma unroll
      for (int j = 0; j < 8; ++j) a[j] = (_Float16)rA0[j];
      const f16x8 b = B0;
      const int tn = (t + 2 < TILES) ? t + 2 : 0;
#pragma unroll
      for (int j = 0; j < 8; ++j)
        rA0[j] = EMIT ? __builtin_nontemporal_load(wp + (size_t)tn * 2048 +
                                                   j * 32)
                      : wp[(size_t)tn * 2048 + j * 32];
      B0 = *reinterpret_cast<const f16x8*>(xp + (size_t)tn * 2048);
      if constexpr (EMIT)
        *reinterpret_cast<f16x8*>(wtp + (size_t)t * 2048) = a;
      if constexpr (MODE == 0) {
        accA = __builtin_amdgcn_mfma_f32_32x32x16_f16(a, b, accA, 0, 0, 0);
      } else {
        const f32x16 pr =
            __builtin_amdgcn_mfma_f32_32x32x16_f16(a, b, z, 0, 0, 0);
        float d0 = pr[0] * cvr[0], d1 = pr[1] * cvr[1];
        float d2 = pr[2] * cvr[2], d3 = pr[3] * cvr[3];
#pragma unroll
        for (int r = 4; r < 16; r += 4) {
          d0 = fmaf(pr[r + 0], cvr[r + 0], d0);
          d1 = fmaf(pr[r + 1], cvr[r + 1], d1);
          d2 = fmaf(pr[r + 2], cvr[r + 2], d2);
          d3 = fmaf(pr[r + 3], cvr[r + 3], d3);
        }
        float dp = (d0 + d1) + (d2 + d3);
        dp += __shfl_xor(dp, 32);
        const float e = __expf(dp);
        lacc += e;
#pragma unroll
        for (int r = 0; r < 16; ++r) accA[r] = fmaf(e, pr[r], accA[r]);
      }
    }
    {
      f16x8 a;
#pragma unroll
      for (int j = 0; j < 8; ++j) a[j] = (_Float16)rA1[j];
      const f16x8 b = B1;
      const int tn = (t + 3 < TILES) ? t + 3 : 0;
#pragma unroll
      for (int j = 0; j < 8; ++j)
        rA1[j] = EMIT ? __builtin_nontemporal_load(wp + (size_t)tn * 2048 +
                                                   j * 32)
                      : wp[(size_t)tn * 2048 + j * 32];
      B1 = *reinterpret_cast<const f16x8*>(xp + (size_t)tn * 2048);
      if constexpr (EMIT)
        *reinterpret_cast<f16x8*>(wtp + (size_t)(t + 1) * 2048) = a;
      if constexpr (MODE == 0) {
        accB = __builtin_amdgcn_mfma_f32_32x32x16_f16(a, b, accB, 0, 0, 0);
      } else {
        const f32x16 pr =
            __builtin_amdgcn_mfma_f32_32x32x16_f16(a, b, z, 0, 0, 0);
        float d0 = pr[0] * cvr[0], d1 = pr[1] * cvr[1];
        float d2 = pr[2] * cvr[2], d3 = pr[3] * cvr[3];
#pragma unroll
        for (int r = 4; r < 16; r += 4) {
          d0 = fmaf(pr[r + 0], cvr[r + 0], d0);
          d1 = fmaf(pr[r + 1], cvr[r + 1], d1);
          d2 = fmaf(pr[r + 2], cvr[r + 2], d2);
          d3 = fmaf(pr[r + 3], cvr[r + 3], d3);
        }
        float dp = (d0 + d1) + (d2 + d3);
        dp += __shfl_xor(dp, 32);
        const float e = __expf(dp);
        lacc += e;
#pragma unroll
        for (int r = 0; r < 16; ++r) accB[r] = fmaf(e, pr[r], accB[r]);
      }
    }
  }
#pragma unroll
  for (int r = 0; r < 16; ++r) accA[r] += accB[r];

#pragma unroll
  for (int r = 0; r < 16; ++r)
    red[w][(r & 3) + 8 * (r >> 2) + 4 * h][m] = accA[r];
  if (MODE && h == 0) lred[w][m] = lacc;
  __syncthreads();

  float* Pp = partials + ((size_t)c * CHUNKS + chunk) * PS;
#pragma unroll
  for (int e = tid; e < 1024; e += 256) {
    const int d = e >> 5, bb = e & 31;
    Pp[e] = red[0][d][bb] + red[1][d][bb] + red[2][d][bb] + red[3][d][bb];
  }
  if (MODE && tid < 32)
    Pp[1024 + tid] = lred[0][tid] + lred[1][tid] + lred[2][tid] + lred[3][tid];
}

__global__ __launch_bounds__(256) void k_sweep_wt(
    const _Float16* __restrict__ Wt, const _Float16* __restrict__ xt,
    const float* __restrict__ cumVec, float* __restrict__ partials) {
  __shared__ float red[4][32][33];
  __shared__ float lred[4][32];
  __shared__ float sCV[32][32];
  const int bid = blockIdx.x;
  const int c = bid & 31;
  const int chunk = bid >> 5;
  const int tid = threadIdx.x;
  for (int e = tid; e < 1024; e += 256)
    sCV[e >> 5][e & 31] = cumVec[(size_t)c * 1024 + e];
  __syncthreads();
  mega_sweep_wt(Wt, xt, sCV, partials, red, lred, c, chunk, tid);
}

template <int K>
__global__ __launch_bounds__(1024) void k_reduce(
    const float* __restrict__ partials, float* __restrict__ CV,
    float* __restrict__ out) {
  const int c = blockIdx.x;
  const int t = threadIdx.x;
  const int b = t >> 5, d = t & 31;
  const float* Pc = partials + (size_t)c * CHUNKS * PS;
  float s = 0.f;
#pragma unroll 4
  for (int ch = 0; ch < CHUNKS; ++ch) s += Pc[(size_t)ch * PS + d * 32 + b];
  float inv;
  if constexpr (K == 0) {
    inv = 1.0f / (float)kN;
  } else {
    float lb = 0.f;
#pragma unroll 4
    for (int ch = 0; ch < CHUNKS; ++ch) lb += Pc[(size_t)ch * PS + 1024 + b];
    inv = 1.0f / lb;
  }
  const float sv = s * inv;
  float sn = sv * sv;
  sn += __shfl_xor(sn, 1);
  sn += __shfl_xor(sn, 2);
  sn += __shfl_xor(sn, 4);
  sn += __shfl_xor(sn, 8);
  sn += __shfl_xor(sn, 16);
  const float coef = sqrtf(sn) / (1.0f + sn);
  const float o = sv * coef;
  if constexpr (K == 2)
    out[(size_t)c * 1024 + t] = o;
  else if constexpr (K == 0)
    CV[(size_t)c * 1024 + t] = o;
  else
    CV[(size_t)c * 1024 + t] += o;
}

// ---------------- v1 single-kernel fallback (no ws; passed @~590us) --------
namespace v1 {
constexpr int BG = 4, NSLOT = 128, THREADS1 = NSLOT * 8;
template <int MODE>
__device__ __forceinline__ void sweep_pass(const float* __restrict__ Wc,
                                           const float* __restrict__ x, int b0,
                                           int tid, int nslot, int dg,
                                           float (*red)[8][20], float (*sS)[kD],
                                           float* sL, const float (*sVec)[kD]) {
  float acc[BG][4];
  float lv[BG];
#pragma unroll
  for (int b = 0; b < BG; ++b) {
    lv[b] = 0.f;
#pragma unroll
    for (int j = 0; j < 4; ++j) acc[b][j] = 0.f;
  }
  float vec[BG][4];
  if (MODE) {
#pragma unroll
    for (int b = 0; b < BG; ++b)
#pragma unroll
      for (int j = 0; j < 4; ++j) vec[b][j] = sVec[b][4 * dg + j];
  }
#pragma unroll 1
  for (int n = nslot; n < kN; n += NSLOT) {
    const float* Wn = Wc + (size_t)n * (kI * kD) + 4 * dg;
    float pr[BG][4];
#pragma unroll
    for (int b = 0; b < BG; ++b)
#pragma unroll
      for (int j = 0; j < 4; ++j) pr[b][j] = 0.f;
#pragma unroll
    for (int iq = 0; iq < 4; ++iq) {
      float4 wv[4];
#pragma unroll
      for (int r = 0; r < 4; ++r)
        wv[r] = *reinterpret_cast<const float4*>(Wn + (4 * iq + r) * kD);
#pragma unroll
      for (int b = 0; b < BG; ++b) {
        const float4 xv = *reinterpret_cast<const float4*>(
            x + ((size_t)(b0 + b) * kN + n) * kI + 4 * iq);
        const float xsv[4] = {xv.x, xv.y, xv.z, xv.w};
#pragma unroll
        for (int r = 0; r < 4; ++r) {
          pr[b][0] = fmaf(xsv[r], wv[r].x, pr[b][0]);
          pr[b][1] = fmaf(xsv[r], wv[r].y, pr[b][1]);
          pr[b][2] = fmaf(xsv[r], wv[r].z, pr[b][2]);
          pr[b][3] = fmaf(xsv[r], wv[r].w, pr[b][3]);
        }
      }
    }
    if (MODE == 0) {
#pragma unroll
      for (int b = 0; b < BG; ++b)
#pragma unroll
        for (int j = 0; j < 4; ++j) acc[b][j] += pr[b][j];
    } else {
#pragma unroll
      for (int b = 0; b < BG; ++b) {
        float dp = pr[b][0] * vec[b][0] + pr[b][1] * vec[b][1] +
                   pr[b][2] * vec[b][2] + pr[b][3] * vec[b][3];
        dp += __shfl_xor(dp, 1);
        dp += __shfl_xor(dp, 2);
        dp += __shfl_xor(dp, 4);
        const float e = __expf(dp);
        lv[b] += e;
        acc[b][0] = fmaf(e, pr[b][0], acc[b][0]);
        acc[b][1] = fmaf(e, pr[b][1], acc[b][1]);
        acc[b][2] = fmaf(e, pr[b][2], acc[b][2]);
        acc[b][3] = fmaf(e, pr[b][3], acc[b][3]);
      }
    }
  }
#pragma unroll
  for (int b = 0; b < BG; ++b) {
#pragma unroll
    for (int j = 0; j < 4; ++j) {
      float v = acc[b][j];
      v += __shfl_xor(v, 8);
      v += __shfl_xor(v, 16);
      v += __shfl_xor(v, 32);
      acc[b][j] = v;
    }
    if (MODE) {
      float v = lv[b];
      v += __shfl_xor(v, 8);
      v += __shfl_xor(v, 16);
      v += __shfl_xor(v, 32);
      lv[b] = v;
    }
  }
  const int lane = tid & 63;
  const int wv_id = tid >> 6;
  if ((lane >> 3) == 0) {
#pragma unroll
    for (int b = 0; b < BG; ++b) {
#pragma unroll
      for (int j = 0; j < 4; ++j) red[wv_id][dg][4 * b + j] = acc[b][j];
      if (MODE) red[wv_id][dg][16 + b] = lv[b];
    }
  }
  __syncthreads();
  if (tid < 128) {
    const int dgc = tid >> 4, e = tid & 15;
    float s = 0.f;
#pragma unroll
    for (int w = 0; w < 16; ++w) s += red[w][dgc][e];
    sS[e >> 2][4 * dgc + (e & 3)] = s;
  }
  if (MODE && tid >= 128 && tid < 128 + BG) {
    const int b = tid - 128;
    float s = 0.f;
#pragma unroll
    for (int w = 0; w < 16; ++w) s += red[w][0][16 + b];
    sL[b] = s;
  }
  __syncthreads();
}

__global__ __launch_bounds__(THREADS1, 4) void caps_route_kernel(
    const float* __restrict__ x, const float* __restrict__ W,
    float* __restrict__ out) {
  __shared__ float red[16][8][20];
  __shared__ float sS[BG][kD];
  __shared__ float sVec[BG][kD];
  __shared__ float sL[BG];
  const int i = blockIdx.x;
  const int xcd = i & 7;
  const int j = i >> 3;
  const int c = xcd + 8 * (j >> 3);
  const int b0 = 4 * (j & 7);
  const int tid = threadIdx.x;
  const int nslot = tid >> 3;
  const int dg = tid & 7;
  const float* Wc = W + (size_t)c * kN * kI * kD;
  sweep_pass<0>(Wc, x, b0, tid, nslot, dg, red, sS, sL, sVec);
  if (tid < BG) {
    const int b = tid;
    float sval[kD], sn = 0.f;
    const float inv = 1.0f / (float)kN;
#pragma unroll
    for (int d = 0; d < kD; ++d) {
      sval[d] = sS[b][d] * inv;
      sn += sval[d] * sval[d];
    }
    const float coef = sqrtf(sn) / (1.0f + sn);
#pragma unroll
    for (int d = 0; d < kD; ++d) sVec[b][d] = sval[d] * coef;
  }
  __syncthreads();
  sweep_pass<1>(Wc, x, b0, tid, nslot, dg, red, sS, sL, sVec);
  if (tid < BG) {
    const int b = tid;
    float sval[kD], sn = 0.f;
    const float inv = 1.0f / sL[b];
#pragma unroll
    for (int d = 0; d < kD; ++d) {
      sval[d] = sS[b][d] * inv;
      sn += sval[d] * sval[d];
    }
    const float coef = sqrtf(sn) / (1.0f + sn);
#pragma unroll
    for (int d = 0; d < kD; ++d) sVec[b][d] += sval[d] * coef;
  }
  __syncthreads();
  sweep_pass<1>(Wc, x, b0, tid, nslot, dg, red, sS, sL, sVec);
  if (tid < BG) {
    const int b = tid;
    float sval[kD], sn = 0.f;
    const float inv = 1.0f / sL[b];
#pragma unroll
    for (int d = 0; d < kD; ++d) {
      sval[d] = sS[b][d] * inv;
      sn += sval[d] * sval[d];
    }
    const float coef = sqrtf(sn) / (1.0f + sn);
    float* o = out + ((size_t)c * kB + (b0 + b)) * kD;
#pragma unroll
    for (int d = 0; d < kD; ++d) o[d] = sval[d] * coef;
  }
}
}  // namespace v1

// ---- mega-path capability probe: run at .so load (never under capture) ----
namespace {
int g_mega_ok = 0;
int probe_mega() {
  int dev = 0;
  if (hipGetDevice(&dev) != hipSuccess) return 0;
  int nCU = 0;
  if (hipDeviceGetAttribute(&nCU, hipDeviceAttributeMultiprocessorCount,
                            dev) != hipSuccess)
    return 0;
  int maxB = 0;
  if (hipOccupancyMaxActiveBlocksPerMultiprocessor(&maxB, k_mega2, 256, 0) !=
      hipSuccess)
    return 0;
  return (nCU > 0 && maxB > 0 && (size_t)nCU * (size_t)maxB >= (size_t)GRID)
             ? 1
             : -1;  // -1: probed OK but not co-resident
}
struct MegaProbeInit {
  MegaProbeInit() { g_mega_ok = probe_mega(); }
} g_mega_probe_init;
}  // namespace

extern "C" void kernel_launch(void* const* d_in, const int* in_sizes, int n_in,
                              void* d_out, int out_size, void* d_ws,
                              size_t ws_size, hipStream_t stream) {
  const float* x = (const float*)d_in[0];  // [B,N,IN] fp32
  const float* W = (const float*)d_in[1];  // [C,N,IN,OUT] fp32
  float* out = (float*)d_out;              // [C,B,1,1,OUT] fp32
  (void)in_sizes; (void)n_in; (void)out_size;

  if (g_mega_ok == 0) g_mega_ok = probe_mega();  // lazy retry if ctor failed

  if (g_mega_ok == 1 && ws_size >= WS_BYTES_MEGA) {
    _Float16* xt = (_Float16*)d_ws;
    _Float16* Wt = xt + XT_ELEMS;
    float* P0 = (float*)(Wt + WT_ELEMS);
    float* P1 = P0 + P_FLOATS;
    float* P2 = P1 + P_FLOATS;
    unsigned* bar = (unsigned*)(P2 + P_FLOATS);  // 16B-aligned; zeroed by k_xt

    k_xt<<<GRID, 256, 0, stream>>>(x, xt, bar);
    k_mega2<<<GRID, 256, 0, stream>>>(W, xt, Wt, P0, P1, P2, bar, out);
    return;
  }

  if (ws_size >= WS_BYTES_BIG) {
    _Float16* xt = (_Float16*)d_ws;
    _Float16* Wt = xt + XT_ELEMS;
    float* P = (float*)(Wt + WT_ELEMS);
    float* CV = P + P_FLOATS;

    k_xt<<<GRID, 256, 0, stream>>>(x, xt, nullptr);
    k_sweep<0, true><<<GRID, 256, 0, stream>>>(W, xt, nullptr, P, Wt);
    k_reduce<0><<<kC, 1024, 0, stream>>>(P, CV, nullptr);
    k_sweep_wt<<<GRID, 256, 0, stream>>>(Wt, xt, CV, P);
    k_reduce<1><<<kC, 1024, 0, stream>>>(P, CV, nullptr);
    k_sweep_wt<<<GRID, 256, 0, stream>>>(Wt, xt, CV, P);
    k_reduce<2><<<kC, 1024, 0, stream>>>(P, nullptr, out);
    return;
  }

  if (ws_size >= WS_BYTES_MID) {
    _Float16* xt = (_Float16*)d_ws;
    float* P = (float*)(xt + XT_ELEMS);
    float* CV = P + P_FLOATS;

    k_xt<<<GRID, 256, 0, stream>>>(x, xt, nullptr);
    k_sweep<0, false><<<GRID, 256, 0, stream>>>(W, xt, nullptr, P, nullptr);
    k_reduce<0><<<kC, 1024, 0, stream>>>(P, CV, nullptr);
    k_sweep<1, false><<<GRID, 256, 0, stream>>>(W, xt, CV, P, nullptr);
    k_reduce<1><<<kC, 1024, 0, stream>>>(P, CV, nullptr);
    k_sweep<1, false><<<GRID, 256, 0, stream>>>(W, xt, CV, P, nullptr);
    k_reduce<2><<<kC, 1024, 0, stream>>>(P, nullptr, out);
    return;
  }

  v1::caps_route_kernel<<<256, v1::THREADS1, 0, stream>>>(x, W, out);
}